// Round 5
// baseline (558.531 us; speedup 1.0000x reference)
//
#include <hip/hip_runtime.h>
#include <hip/hip_bf16.h>
#include <math.h>

typedef __hip_bfloat16  bf16;
typedef __hip_bfloat162 bf162;

#define BSZ     128   // nodes per bucket (dst >> 7)
#define NBMAX   512   // max buckets (N <= 65536)
#define PACHUNK 8192  // edges per partA block

__device__ inline float4 bf4_to_f4(uint2 v) {
  float2 lo = __bfloat1622float2(*(bf162*)&v.x);
  float2 hi = __bfloat1622float2(*(bf162*)&v.y);
  return make_float4(lo.x, lo.y, hi.x, hi.y);
}
__device__ inline uint2 f4_to_bf4(float4 v) {
  bf162 lo = __float22bfloat162_rn(make_float2(v.x, v.y));
  bf162 hi = __float22bfloat162_rn(make_float2(v.z, v.w));
  uint2 r;
  r.x = *(unsigned*)&lo;
  r.y = *(unsigned*)&hi;
  return r;
}

// ---------------- CSR build ----------------
__global__ void k_hist(const int* __restrict__ eiIn, const int* __restrict__ eiOut,
                       int E, int* __restrict__ cur, int N) {
  int e = blockIdx.x * blockDim.x + threadIdx.x;
  if (e >= E) return;
  const int* ei = blockIdx.y ? eiOut : eiIn;
  atomicAdd(cur + blockIdx.y * N + ei[E + e], 1);
}

__global__ __launch_bounds__(1024) void k_scan(int* cur, int* offsI, int* offsO,
                                               int* bucketCur, int N) {
  int* cnt  = cur + blockIdx.x * N;
  int* offs = blockIdx.x ? offsO : offsI;
  __shared__ int wsum[16];
  __shared__ int s_carry, s_total;
  const int t = threadIdx.x, lane = t & 63, wid = t >> 6;
  if (t == 0) s_carry = 0;
  __syncthreads();
  for (int base = 0; base < N; base += 1024) {
    int i = base + t;
    int v = (i < N) ? cnt[i] : 0;
    int incl = v;
    #pragma unroll
    for (int d = 1; d < 64; d <<= 1) {
      int u = __shfl_up(incl, d, 64);
      if (lane >= d) incl += u;
    }
    if (lane == 63) wsum[wid] = incl;
    __syncthreads();
    if (wid == 0) {
      int ws = (lane < 16) ? wsum[lane] : 0;
      int wi = ws;
      #pragma unroll
      for (int d = 1; d < 16; d <<= 1) {
        int u = __shfl_up(wi, d, 64);
        if (lane >= d) wi += u;
      }
      if (lane < 16) wsum[lane] = wi - ws;
      if (lane == 15) s_total = wi;
    }
    __syncthreads();
    int excl = s_carry + wsum[wid] + (incl - v);
    if (i < N) { offs[i] = excl; cnt[i] = excl; }
    __syncthreads();
    if (t == 0) s_carry += s_total;
    __syncthreads();
  }
  if (t == 0) offs[N] = s_carry;
  __syncthreads();
  int NB = (N + BSZ - 1) >> 7;
  for (int b = t; b < NB; b += 1024) bucketCur[blockIdx.x * NBMAX + b] = offs[b << 7];
}

// ---------------- partA: counting-sort edges into bucket-contiguous staging ----------------
__global__ __launch_bounds__(256) void k_partA(const int* __restrict__ eiIn, const float* __restrict__ ewIn,
                                               const int* __restrict__ eiOut, const float* __restrict__ ewOut,
                                               int E, int* __restrict__ bucketCur,
                                               int2* __restrict__ sI, int2* __restrict__ sO, int NB) {
  __shared__ int2 staged[PACHUNK];
  __shared__ int cnt[NBMAX];
  __shared__ int sb[NBMAX];
  const int t = threadIdx.x;
  const int set = blockIdx.y;
  const int*   ei = set ? eiOut : eiIn;
  const float* ew = set ? ewOut : ewIn;
  int2* stg  = set ? sO : sI;
  int*  bcur = bucketCur + set * NBMAX;
  const int base = blockIdx.x * PACHUNK;
  const int m = min(PACHUNK, E - base);
  for (int b = t; b < NB; b += 256) cnt[b] = 0;
  __syncthreads();
  #pragma unroll 4
  for (int r = 0; r < PACHUNK / 256; ++r) {
    int i = r * 256 + t;
    if (i < m) atomicAdd(&cnt[ei[E + base + i] >> 7], 1);
  }
  __syncthreads();
  if (t < 64) {
    int carry = 0;
    int nch = (NB + 63) >> 6;
    for (int c = 0; c < nch; ++c) {
      int idx = c * 64 + t;
      int v = (idx < NB) ? cnt[idx] : 0;
      int incl = v;
      #pragma unroll
      for (int d = 1; d < 64; d <<= 1) {
        int u = __shfl_up(incl, d, 64);
        if (t >= d) incl += u;
      }
      if (idx < NB) sb[idx] = carry + incl - v;
      carry += __shfl(incl, 63, 64);
    }
  }
  __syncthreads();
  for (int b = t; b < NB; b += 256) {
    int c = cnt[b];
    if (c > 0) cnt[b] = atomicAdd(&bcur[b], c) - sb[b];
  }
  __syncthreads();
  #pragma unroll 4
  for (int r = 0; r < PACHUNK / 256; ++r) {
    int i = r * 256 + t;
    if (i < m) {
      int src = ei[base + i];
      int dst = ei[E + base + i];
      float w = ew[base + i];
      int b = dst >> 7;
      int rank = atomicAdd(&sb[b], 1);
      staged[rank] = make_int2(src | ((dst & 127) << 16) | (b << 23), __float_as_int(w));
    }
  }
  __syncthreads();
  #pragma unroll 4
  for (int r = 0; r < PACHUNK / 256; ++r) {
    int j = r * 256 + t;
    if (j < m) {
      int2 p = staged[j];
      int b = ((unsigned)p.x) >> 23;
      stg[cnt[b] + j] = p;
    }
  }
}

// ---------------- partB: bucket staging -> final CSR order ----------------
__global__ __launch_bounds__(256) void k_partB(const int* __restrict__ offsI, const int* __restrict__ offsO,
                                               const int2* __restrict__ sI, const int2* __restrict__ sO,
                                               int2* __restrict__ eI, int2* __restrict__ eO, int N) {
  __shared__ int cur[BSZ];
  const int t = threadIdx.x;
  const int b = blockIdx.x;
  const int set = blockIdx.y;
  const int*  offs = set ? offsO : offsI;
  const int2* stg  = set ? sO : sI;
  int2* out = set ? eO : eI;
  int nlo = b << 7;
  int cnt = min(BSZ, N - nlo);
  if (t < cnt) cur[t] = offs[nlo + t];
  __syncthreads();
  int lo = offs[nlo], hi = offs[nlo + cnt];
  for (int i = lo + t; i < hi; i += 256) {
    int2 p = stg[i];
    int dl = (p.x >> 16) & 127;
    int pos = atomicAdd(&cur[dl], 1);
    out[pos] = make_int2(p.x & 0xffff, p.y);
  }
}

// ---------------- weight prep ----------------
__global__ void k_wprep(const float* __restrict__ Wmi0, const float* __restrict__ Wmo0, const float* __restrict__ Ws0,
                        const float* __restrict__ Wmi1, const float* __restrict__ Wmo1, const float* __restrict__ Ws1,
                        const float* __restrict__ resW,
                        const float* __restrict__ bmi0, const float* __restrict__ bsi0,
                        const float* __restrict__ bmo0, const float* __restrict__ bso0,
                        const float* __restrict__ bmi1, const float* __restrict__ bsi1,
                        const float* __restrict__ bmo1, const float* __restrict__ bso1,
                        float* __restrict__ W0I, float* __restrict__ W0O, float* __restrict__ Wcat1,
                        float* __restrict__ bi0, float* __restrict__ bo0,
                        float* __restrict__ bi1, float* __restrict__ bo1) {
  int i = blockIdx.x * blockDim.x + threadIdx.x;
  if (i < 128 * 128) {
    W0I[i] = Wmi0[i] + Ws0[i];
    W0O[i] = Wmo0[i] + Ws0[i];
  }
  if (i < 128 * 192) {
    int k = i / 192, n = i % 192;
    float v;
    if (n < 64)       v = Wmi1[k * 64 + n]       + Ws1[k * 64 + n];
    else if (n < 128) v = Wmo1[k * 64 + n - 64]  + Ws1[k * 64 + n - 64];
    else              v = resW[k * 64 + n - 128];
    Wcat1[k * 192 + n] = v;
  }
  if (i < 128) { bi0[i] = bmi0[i] + bsi0[i]; bo0[i] = bmo0[i] + bso0[i]; }
  if (i < 64)  { bi1[i] = bmi1[i] + bsi1[i]; bo1[i] = bmo1[i] + bso1[i]; }
}

// ---------------- h0 table: bf16(x + pe) ----------------
__global__ void k_prep0(const float* __restrict__ x, const float* __restrict__ pe,
                        bf16* __restrict__ h0, int total) {
  int i = blockIdx.x * blockDim.x + threadIdx.x;
  if (i < total) h0[i] = __float2bfloat16(x[i] + pe[i & 127]);
}

// ---------------- layer-0 gather: aggI/aggO = prop(h0) over eI/eO (pre-transform, commuted) ----------------
// half-wave per edge, 4 cols/lane (dwordx2 bf16x4 loads); table row = 256 B.
__global__ __launch_bounds__(256) void k_agg0(const bf16* __restrict__ tb,
                                              const int* __restrict__ offsI, const int2* __restrict__ eI,
                                              const int* __restrict__ offsO, const int2* __restrict__ eO,
                                              float* __restrict__ aggI, float* __restrict__ aggO, int N) {
  int n = (blockIdx.x * blockDim.x + threadIdx.x) >> 6;
  int lane = threadIdx.x & 63;
  if (n >= N) return;
  const int sub = lane >> 5, sl = lane & 31;
  const char* base = (const char*)tb + sl * 8;
  float i0 = 0, i1 = 0, i2 = 0, i3 = 0, o0 = 0, o1 = 0, o2 = 0, o3 = 0;
  {
    int s0 = offsI[n], s1 = offsI[n + 1];
    int i = s0 + sub;
    for (; i + 6 < s1; i += 8) {
      int2 eA = eI[i], eB = eI[i + 2], eC = eI[i + 4], eD = eI[i + 6];
      float4 vA = bf4_to_f4(*(const uint2*)(base + ((size_t)(unsigned)eA.x << 8)));
      float4 vB = bf4_to_f4(*(const uint2*)(base + ((size_t)(unsigned)eB.x << 8)));
      float4 vC = bf4_to_f4(*(const uint2*)(base + ((size_t)(unsigned)eC.x << 8)));
      float4 vD = bf4_to_f4(*(const uint2*)(base + ((size_t)(unsigned)eD.x << 8)));
      float wA = __int_as_float(eA.y), wB = __int_as_float(eB.y);
      float wC = __int_as_float(eC.y), wD = __int_as_float(eD.y);
      i0 += wA * vA.x + wB * vB.x + wC * vC.x + wD * vD.x;
      i1 += wA * vA.y + wB * vB.y + wC * vC.y + wD * vD.y;
      i2 += wA * vA.z + wB * vB.z + wC * vC.z + wD * vD.z;
      i3 += wA * vA.w + wB * vB.w + wC * vC.w + wD * vD.w;
    }
    for (; i < s1; i += 2) {
      int2 e = eI[i];
      float4 v = bf4_to_f4(*(const uint2*)(base + ((size_t)(unsigned)e.x << 8)));
      float w = __int_as_float(e.y);
      i0 += w * v.x; i1 += w * v.y; i2 += w * v.z; i3 += w * v.w;
    }
  }
  {
    int s0 = offsO[n], s1 = offsO[n + 1];
    int i = s0 + sub;
    for (; i + 6 < s1; i += 8) {
      int2 eA = eO[i], eB = eO[i + 2], eC = eO[i + 4], eD = eO[i + 6];
      float4 vA = bf4_to_f4(*(const uint2*)(base + ((size_t)(unsigned)eA.x << 8)));
      float4 vB = bf4_to_f4(*(const uint2*)(base + ((size_t)(unsigned)eB.x << 8)));
      float4 vC = bf4_to_f4(*(const uint2*)(base + ((size_t)(unsigned)eC.x << 8)));
      float4 vD = bf4_to_f4(*(const uint2*)(base + ((size_t)(unsigned)eD.x << 8)));
      float wA = __int_as_float(eA.y), wB = __int_as_float(eB.y);
      float wC = __int_as_float(eC.y), wD = __int_as_float(eD.y);
      o0 += wA * vA.x + wB * vB.x + wC * vC.x + wD * vD.x;
      o1 += wA * vA.y + wB * vB.y + wC * vC.y + wD * vD.y;
      o2 += wA * vA.z + wB * vB.z + wC * vC.z + wD * vD.z;
      o3 += wA * vA.w + wB * vB.w + wC * vC.w + wD * vD.w;
    }
    for (; i < s1; i += 2) {
      int2 e = eO[i];
      float4 v = bf4_to_f4(*(const uint2*)(base + ((size_t)(unsigned)e.x << 8)));
      float w = __int_as_float(e.y);
      o0 += w * v.x; o1 += w * v.y; o2 += w * v.z; o3 += w * v.w;
    }
  }
  i0 += __shfl_xor(i0, 32, 64); i1 += __shfl_xor(i1, 32, 64);
  i2 += __shfl_xor(i2, 32, 64); i3 += __shfl_xor(i3, 32, 64);
  o0 += __shfl_xor(o0, 32, 64); o1 += __shfl_xor(o1, 32, 64);
  o2 += __shfl_xor(o2, 32, 64); o3 += __shfl_xor(o3, 32, 64);
  if (sub == 0) {
    *(float4*)(aggI + (size_t)n * 128 + sl * 4) = make_float4(i0, i1, i2, i3);
    *(float4*)(aggO + (size_t)n * 128 + sl * 4) = make_float4(o0, o1, o2, o3);
  }
}

// ---------------- layer-0 dual GEMM + full epilogue -> h1 (bf16) ----------------
// h1 = tanh(ci*(aggI@W0I + bi) + co*(aggO@W0O + bo) + x + pe)
__global__ __launch_bounds__(256) void k_gemmL0(const float* __restrict__ aggI, const float* __restrict__ aggO,
                                                const float* __restrict__ W0I, const float* __restrict__ W0O,
                                                const float* __restrict__ bi, const float* __restrict__ bo,
                                                const float* __restrict__ cin, const float* __restrict__ cou,
                                                const float* __restrict__ x, const float* __restrict__ pe,
                                                bf16* __restrict__ h1, int N) {
  __shared__ float AstI[64][65], AstO[64][65];
  __shared__ float BsI[64][68], BsO[64][68];
  const int t  = threadIdx.x;
  const int bm = blockIdx.x * 64;
  const int bn = blockIdx.y * 64;
  const int tx = t & 15, ty = t >> 4;
  const int sr = t >> 4;
  const int sc = (t & 15) * 4;
  float accI[4][4] = {}, accO[4][4] = {};
  for (int kc = 0; kc < 128; kc += 64) {
    __syncthreads();
    #pragma unroll
    for (int j = 0; j < 4; ++j) {
      int r = j * 16 + sr;
      int gm = bm + r;
      float4 vI = make_float4(0.f, 0.f, 0.f, 0.f), vO = vI;
      if (gm < N) {
        vI = *(const float4*)(aggI + (size_t)gm * 128 + kc + sc);
        vO = *(const float4*)(aggO + (size_t)gm * 128 + kc + sc);
      }
      AstI[sc + 0][r] = vI.x; AstI[sc + 1][r] = vI.y; AstI[sc + 2][r] = vI.z; AstI[sc + 3][r] = vI.w;
      AstO[sc + 0][r] = vO.x; AstO[sc + 1][r] = vO.y; AstO[sc + 2][r] = vO.z; AstO[sc + 3][r] = vO.w;
      *(float4*)(&BsI[r][sc]) = *(const float4*)(W0I + (size_t)(kc + r) * 128 + bn + sc);
      *(float4*)(&BsO[r][sc]) = *(const float4*)(W0O + (size_t)(kc + r) * 128 + bn + sc);
    }
    __syncthreads();
    #pragma unroll 4
    for (int k = 0; k < 64; ++k) {
      float4 aI = *(const float4*)(&AstI[k][ty * 4]);
      float4 aO = *(const float4*)(&AstO[k][ty * 4]);
      float4 bI = *(const float4*)(&BsI[k][tx * 4]);
      float4 bO = *(const float4*)(&BsO[k][tx * 4]);
      accI[0][0] = fmaf(aI.x, bI.x, accI[0][0]); accI[0][1] = fmaf(aI.x, bI.y, accI[0][1]);
      accI[0][2] = fmaf(aI.x, bI.z, accI[0][2]); accI[0][3] = fmaf(aI.x, bI.w, accI[0][3]);
      accI[1][0] = fmaf(aI.y, bI.x, accI[1][0]); accI[1][1] = fmaf(aI.y, bI.y, accI[1][1]);
      accI[1][2] = fmaf(aI.y, bI.z, accI[1][2]); accI[1][3] = fmaf(aI.y, bI.w, accI[1][3]);
      accI[2][0] = fmaf(aI.z, bI.x, accI[2][0]); accI[2][1] = fmaf(aI.z, bI.y, accI[2][1]);
      accI[2][2] = fmaf(aI.z, bI.z, accI[2][2]); accI[2][3] = fmaf(aI.z, bI.w, accI[2][3]);
      accI[3][0] = fmaf(aI.w, bI.x, accI[3][0]); accI[3][1] = fmaf(aI.w, bI.y, accI[3][1]);
      accI[3][2] = fmaf(aI.w, bI.z, accI[3][2]); accI[3][3] = fmaf(aI.w, bI.w, accI[3][3]);
      accO[0][0] = fmaf(aO.x, bO.x, accO[0][0]); accO[0][1] = fmaf(aO.x, bO.y, accO[0][1]);
      accO[0][2] = fmaf(aO.x, bO.z, accO[0][2]); accO[0][3] = fmaf(aO.x, bO.w, accO[0][3]);
      accO[1][0] = fmaf(aO.y, bO.x, accO[1][0]); accO[1][1] = fmaf(aO.y, bO.y, accO[1][1]);
      accO[1][2] = fmaf(aO.y, bO.z, accO[1][2]); accO[1][3] = fmaf(aO.y, bO.w, accO[1][3]);
      accO[2][0] = fmaf(aO.z, bO.x, accO[2][0]); accO[2][1] = fmaf(aO.z, bO.y, accO[2][1]);
      accO[2][2] = fmaf(aO.z, bO.z, accO[2][2]); accO[2][3] = fmaf(aO.z, bO.w, accO[2][3]);
      accO[3][0] = fmaf(aO.w, bO.x, accO[3][0]); accO[3][1] = fmaf(aO.w, bO.y, accO[3][1]);
      accO[3][2] = fmaf(aO.w, bO.z, accO[3][2]); accO[3][3] = fmaf(aO.w, bO.w, accO[3][3]);
    }
  }
  const int col = bn + tx * 4;
  float4 bif = *(const float4*)(bi + col);
  float4 bof = *(const float4*)(bo + col);
  float4 pv  = *(const float4*)(pe + col);
  #pragma unroll
  for (int i = 0; i < 4; ++i) {
    int gm = bm + ty * 4 + i;
    if (gm < N) {
      float ci = cin[gm], co = cou[gm];
      float4 xv = *(const float4*)(x + (size_t)gm * 128 + col);
      float4 v;
      v.x = tanhf(ci * (accI[i][0] + bif.x) + co * (accO[i][0] + bof.x) + xv.x + pv.x);
      v.y = tanhf(ci * (accI[i][1] + bif.y) + co * (accO[i][1] + bof.y) + xv.y + pv.y);
      v.z = tanhf(ci * (accI[i][2] + bif.z) + co * (accO[i][2] + bof.z) + xv.z + pv.z);
      v.w = tanhf(ci * (accI[i][3] + bif.w) + co * (accO[i][3] + bof.w) + xv.w + pv.w);
      *(uint2*)(h1 + (size_t)gm * 128 + col) = f4_to_bf4(v);
    }
  }
}

// ---------------- layer-1 GEMM: [t1g | t1r] = h1(bf16) @ Wcat1, split outputs ----------------
__global__ __launch_bounds__(256) void k_gemm1(const bf16* __restrict__ A,
                                               const float* __restrict__ W,
                                               bf16* __restrict__ t1g, bf16* __restrict__ t1r, int N) {
  __shared__ float Ast[64][65];
  __shared__ float Bs[64][68];
  const int t  = threadIdx.x;
  const int bm = blockIdx.x * 64;
  const int bn = blockIdx.y * 64;
  const int tx = t & 15, ty = t >> 4;
  const int sr = t >> 4;
  const int sc = (t & 15) * 4;
  float acc[4][4] = {};
  for (int kc = 0; kc < 128; kc += 64) {
    __syncthreads();
    #pragma unroll
    for (int j = 0; j < 4; ++j) {
      int r = j * 16 + sr;
      int gm = bm + r;
      uint2 raw = make_uint2(0u, 0u);
      if (gm < N) raw = *(const uint2*)((const char*)A + (size_t)gm * 256 + (kc + sc) * 2);
      float4 v = bf4_to_f4(raw);
      Ast[sc + 0][r] = v.x; Ast[sc + 1][r] = v.y;
      Ast[sc + 2][r] = v.z; Ast[sc + 3][r] = v.w;
      *(float4*)(&Bs[r][sc]) = *(const float4*)(W + (size_t)(kc + r) * 192 + bn + sc);
    }
    __syncthreads();
    #pragma unroll 8
    for (int k = 0; k < 64; ++k) {
      float4 a = *(const float4*)(&Ast[k][ty * 4]);
      float4 b = *(const float4*)(&Bs[k][tx * 4]);
      acc[0][0] = fmaf(a.x, b.x, acc[0][0]); acc[0][1] = fmaf(a.x, b.y, acc[0][1]);
      acc[0][2] = fmaf(a.x, b.z, acc[0][2]); acc[0][3] = fmaf(a.x, b.w, acc[0][3]);
      acc[1][0] = fmaf(a.y, b.x, acc[1][0]); acc[1][1] = fmaf(a.y, b.y, acc[1][1]);
      acc[1][2] = fmaf(a.y, b.z, acc[1][2]); acc[1][3] = fmaf(a.y, b.w, acc[1][3]);
      acc[2][0] = fmaf(a.z, b.x, acc[2][0]); acc[2][1] = fmaf(a.z, b.y, acc[2][1]);
      acc[2][2] = fmaf(a.z, b.z, acc[2][2]); acc[2][3] = fmaf(a.z, b.w, acc[2][3]);
      acc[3][0] = fmaf(a.w, b.x, acc[3][0]); acc[3][1] = fmaf(a.w, b.y, acc[3][1]);
      acc[3][2] = fmaf(a.w, b.z, acc[3][2]); acc[3][3] = fmaf(a.w, b.w, acc[3][3]);
    }
  }
  const int col = bn + tx * 4;
  #pragma unroll
  for (int i = 0; i < 4; ++i) {
    int gm = bm + ty * 4 + i;
    if (gm < N) {
      uint2 packed = f4_to_bf4(make_float4(acc[i][0], acc[i][1], acc[i][2], acc[i][3]));
      if (col < 128) *(uint2*)(t1g + (size_t)gm * 128 + col)        = packed;
      else           *(uint2*)(t1r + (size_t)gm * 64 + (col - 128)) = packed;
    }
  }
}

// ---------------- layer-1 gather + epilogue -> h2 (fp32), emb ----------------
// quarter-wave per edge, 4 cols/lane; t1g row = 256 B (in cols 0-63, out cols 64-127).
__global__ __launch_bounds__(256) void k_agg1(const bf16* __restrict__ t1g, const bf16* __restrict__ t1r,
                                              const int* __restrict__ offsI, const int2* __restrict__ eI,
                                              const int* __restrict__ offsO, const int2* __restrict__ eO,
                                              const float* __restrict__ bi, const float* __restrict__ bo,
                                              const float* __restrict__ resb,
                                              const float* __restrict__ cin, const float* __restrict__ cou,
                                              float* __restrict__ h2, float* __restrict__ emb, int N) {
  int n = (blockIdx.x * blockDim.x + threadIdx.x) >> 6;
  int lane = threadIdx.x & 63;
  if (n >= N) return;
  const int sub = lane >> 4;
  const int sl  = lane & 15;
  const char* baseI = (const char*)t1g + sl * 8;
  const char* baseO = baseI + 128;
  float i0 = 0, i1 = 0, i2 = 0, i3 = 0, o0 = 0, o1 = 0, o2 = 0, o3 = 0;
  {
    int s0 = offsI[n], s1 = offsI[n + 1];
    int i = s0 + sub;
    for (; i + 4 < s1; i += 8) {
      int2 eA = eI[i], eB = eI[i + 4];
      float4 vA = bf4_to_f4(*(const uint2*)(baseI + ((size_t)(unsigned)eA.x << 8)));
      float4 vB = bf4_to_f4(*(const uint2*)(baseI + ((size_t)(unsigned)eB.x << 8)));
      float wA = __int_as_float(eA.y), wB = __int_as_float(eB.y);
      i0 += wA * vA.x + wB * vB.x;
      i1 += wA * vA.y + wB * vB.y;
      i2 += wA * vA.z + wB * vB.z;
      i3 += wA * vA.w + wB * vB.w;
    }
    for (; i < s1; i += 4) {
      int2 e = eI[i];
      float4 v = bf4_to_f4(*(const uint2*)(baseI + ((size_t)(unsigned)e.x << 8)));
      float w = __int_as_float(e.y);
      i0 += w * v.x; i1 += w * v.y; i2 += w * v.z; i3 += w * v.w;
    }
  }
  {
    int s0 = offsO[n], s1 = offsO[n + 1];
    int i = s0 + sub;
    for (; i + 4 < s1; i += 8) {
      int2 eA = eO[i], eB = eO[i + 4];
      float4 vA = bf4_to_f4(*(const uint2*)(baseO + ((size_t)(unsigned)eA.x << 8)));
      float4 vB = bf4_to_f4(*(const uint2*)(baseO + ((size_t)(unsigned)eB.x << 8)));
      float wA = __int_as_float(eA.y), wB = __int_as_float(eB.y);
      o0 += wA * vA.x + wB * vB.x;
      o1 += wA * vA.y + wB * vB.y;
      o2 += wA * vA.z + wB * vB.z;
      o3 += wA * vA.w + wB * vB.w;
    }
    for (; i < s1; i += 4) {
      int2 e = eO[i];
      float4 v = bf4_to_f4(*(const uint2*)(baseO + ((size_t)(unsigned)e.x << 8)));
      float w = __int_as_float(e.y);
      o0 += w * v.x; o1 += w * v.y; o2 += w * v.z; o3 += w * v.w;
    }
  }
  i0 += __shfl_xor(i0, 32, 64); i1 += __shfl_xor(i1, 32, 64);
  i2 += __shfl_xor(i2, 32, 64); i3 += __shfl_xor(i3, 32, 64);
  o0 += __shfl_xor(o0, 32, 64); o1 += __shfl_xor(o1, 32, 64);
  o2 += __shfl_xor(o2, 32, 64); o3 += __shfl_xor(o3, 32, 64);
  i0 += __shfl_xor(i0, 16, 64); i1 += __shfl_xor(i1, 16, 64);
  i2 += __shfl_xor(i2, 16, 64); i3 += __shfl_xor(i3, 16, 64);
  o0 += __shfl_xor(o0, 16, 64); o1 += __shfl_xor(o1, 16, 64);
  o2 += __shfl_xor(o2, 16, 64); o3 += __shfl_xor(o3, 16, 64);
  if (sub == 0) {
    const int c = sl * 4;
    float ci = cin[n], co = cou[n];
    float4 bif = *(const float4*)(bi + c);
    float4 bof = *(const float4*)(bo + c);
    float4 rbf = *(const float4*)(resb + c);
    float4 rv  = bf4_to_f4(*(const uint2*)((const char*)t1r + (size_t)n * 128 + sl * 8));
    float4 v;
    v.x = tanhf(ci * (i0 + bif.x) + co * (o0 + bof.x) + rv.x + rbf.x);
    v.y = tanhf(ci * (i1 + bif.y) + co * (o1 + bof.y) + rv.y + rbf.y);
    v.z = tanhf(ci * (i2 + bif.z) + co * (o2 + bof.z) + rv.z + rbf.z);
    v.w = tanhf(ci * (i3 + bif.w) + co * (o3 + bof.w) + rv.w + rbf.w);
    *(float4*)(h2 + (size_t)n * 64 + c) = v;
    float q = v.x * v.x + v.y * v.y + v.z * v.z + v.w * v.w;
    #pragma unroll
    for (int d = 1; d < 16; d <<= 1) q += __shfl_xor(q, d, 64);
    float inv = 1.0f / (sqrtf(q) + 1e-12f);
    *(float4*)(emb + (size_t)n * 64 + c) = make_float4(v.x * inv, v.y * inv, v.z * inv, v.w * inv);
  }
}

// ---------------- decoder as register-tiled GEMM + fused log_softmax ----------------
__global__ __launch_bounds__(256) void k_dec(const float* __restrict__ h2,
                                             const float* __restrict__ Wd, const float* __restrict__ bd,
                                             float* __restrict__ logp, int N) {
  __shared__ float Ht[64][65];
  __shared__ float Bs[64][132];
  __shared__ float sb[128];
  const int t  = threadIdx.x;
  const int bm = blockIdx.x * 64;
  const int tx = t & 15, ty = t >> 4;
  const int sr = t >> 4;
  const int sc = (t & 15) * 4;
  #pragma unroll
  for (int j = 0; j < 4; ++j) {
    int r = j * 16 + sr;
    int gm = bm + r;
    float4 v = make_float4(0.f, 0.f, 0.f, 0.f);
    if (gm < N) v = *(const float4*)(h2 + (size_t)gm * 64 + sc);
    Ht[sc + 0][r] = v.x; Ht[sc + 1][r] = v.y;
    Ht[sc + 2][r] = v.z; Ht[sc + 3][r] = v.w;
    const float* wrow = Wd + (size_t)r * 128 + tx * 8;
    *(float4*)(&Bs[r][tx * 8])     = *(const float4*)(wrow);
    *(float4*)(&Bs[r][tx * 8 + 4]) = *(const float4*)(wrow + 4);
  }
  if (t < 128) sb[t] = bd[t];
  __syncthreads();
  float acc[4][8] = {};
  #pragma unroll 8
  for (int k = 0; k < 64; ++k) {
    float4 a  = *(const float4*)(&Ht[k][ty * 4]);
    float4 b0 = *(const float4*)(&Bs[k][tx * 4]);
    float4 b1 = *(const float4*)(&Bs[k][64 + tx * 4]);
    acc[0][0] = fmaf(a.x, b0.x, acc[0][0]); acc[0][1] = fmaf(a.x, b0.y, acc[0][1]);
    acc[0][2] = fmaf(a.x, b0.z, acc[0][2]); acc[0][3] = fmaf(a.x, b0.w, acc[0][3]);
    acc[0][4] = fmaf(a.x, b1.x, acc[0][4]); acc[0][5] = fmaf(a.x, b1.y, acc[0][5]);
    acc[0][6] = fmaf(a.x, b1.z, acc[0][6]); acc[0][7] = fmaf(a.x, b1.w, acc[0][7]);
    acc[1][0] = fmaf(a.y, b0.x, acc[1][0]); acc[1][1] = fmaf(a.y, b0.y, acc[1][1]);
    acc[1][2] = fmaf(a.y, b0.z, acc[1][2]); acc[1][3] = fmaf(a.y, b0.w, acc[1][3]);
    acc[1][4] = fmaf(a.y, b1.x, acc[1][4]); acc[1][5] = fmaf(a.y, b1.y, acc[1][5]);
    acc[1][6] = fmaf(a.y, b1.z, acc[1][6]); acc[1][7] = fmaf(a.y, b1.w, acc[1][7]);
    acc[2][0] = fmaf(a.z, b0.x, acc[2][0]); acc[2][1] = fmaf(a.z, b0.y, acc[2][1]);
    acc[2][2] = fmaf(a.z, b0.z, acc[2][2]); acc[2][3] = fmaf(a.z, b0.w, acc[2][3]);
    acc[2][4] = fmaf(a.z, b1.x, acc[2][4]); acc[2][5] = fmaf(a.z, b1.y, acc[2][5]);
    acc[2][6] = fmaf(a.z, b1.z, acc[2][6]); acc[2][7] = fmaf(a.z, b1.w, acc[2][7]);
    acc[3][0] = fmaf(a.w, b0.x, acc[3][0]); acc[3][1] = fmaf(a.w, b0.y, acc[3][1]);
    acc[3][2] = fmaf(a.w, b0.z, acc[3][2]); acc[3][3] = fmaf(a.w, b0.w, acc[3][3]);
    acc[3][4] = fmaf(a.w, b1.x, acc[3][4]); acc[3][5] = fmaf(a.w, b1.y, acc[3][5]);
    acc[3][6] = fmaf(a.w, b1.z, acc[3][6]); acc[3][7] = fmaf(a.w, b1.w, acc[3][7]);
  }
  float bb[8];
  #pragma unroll
  for (int j = 0; j < 4; ++j) { bb[j] = sb[tx * 4 + j]; bb[4 + j] = sb[64 + tx * 4 + j]; }
  #pragma unroll
  for (int i = 0; i < 4; ++i) {
    int gm = bm + ty * 4 + i;
    float v[8];
    #pragma unroll
    for (int j = 0; j < 8; ++j) v[j] = acc[i][j] + bb[j];
    float m = v[0];
    #pragma unroll
    for (int j = 1; j < 8; ++j) m = fmaxf(m, v[j]);
    #pragma unroll
    for (int d = 1; d < 16; d <<= 1) m = fmaxf(m, __shfl_xor(m, d, 64));
    float s = 0.f;
    #pragma unroll
    for (int j = 0; j < 8; ++j) s += __expf(v[j] - m);
    #pragma unroll
    for (int d = 1; d < 16; d <<= 1) s += __shfl_xor(s, d, 64);
    float lse = m + __logf(s);
    if (gm < N) {
      float4 o0 = make_float4(v[0] - lse, v[1] - lse, v[2] - lse, v[3] - lse);
      float4 o1 = make_float4(v[4] - lse, v[5] - lse, v[6] - lse, v[7] - lse);
      *(float4*)(logp + (size_t)gm * 128 + tx * 4)      = o0;
      *(float4*)(logp + (size_t)gm * 128 + 64 + tx * 4) = o1;
    }
  }
}

extern "C" void kernel_launch(void* const* d_in, const int* in_sizes, int n_in,
                              void* d_out, int out_size, void* d_ws, size_t ws_size,
                              hipStream_t stream) {
  const float* x     = (const float*)d_in[0];
  const int*   ei_in = (const int*)d_in[1];
  const float* ew_in = (const float*)d_in[2];
  const int*   ei_ou = (const int*)d_in[3];
  const float* ew_ou = (const float*)d_in[4];
  const float* pe    = (const float*)d_in[5];
  const float* Wmi0  = (const float*)d_in[6];
  const float* Wmo0  = (const float*)d_in[7];
  const float* Wsh0  = (const float*)d_in[8];
  const float* bmi0  = (const float*)d_in[9];
  const float* bmo0  = (const float*)d_in[10];
  const float* bsi0  = (const float*)d_in[11];
  const float* bso0  = (const float*)d_in[12];
  const float* cin0  = (const float*)d_in[13];
  const float* cou0  = (const float*)d_in[14];
  const float* Wmi1  = (const float*)d_in[15];
  const float* Wmo1  = (const float*)d_in[16];
  const float* Wsh1  = (const float*)d_in[17];
  const float* bmi1  = (const float*)d_in[18];
  const float* bmo1  = (const float*)d_in[19];
  const float* bsi1  = (const float*)d_in[20];
  const float* bso1  = (const float*)d_in[21];
  const float* cin1  = (const float*)d_in[22];
  const float* cou1  = (const float*)d_in[23];
  const float* resW  = (const float*)d_in[24];
  const float* resb  = (const float*)d_in[25];
  const float* Wd    = (const float*)d_in[26];
  const float* bd    = (const float*)d_in[27];

  const int N = in_sizes[0] / 128;
  const int E = in_sizes[2];
  const int NB = (N + BSZ - 1) >> 7;

  char* ws = (char*)d_ws;
  size_t off = 0;
  auto alloc = [&](size_t bytes) -> char* {
    off = (off + 255) & ~(size_t)255;
    char* p = ws + off;
    off += bytes;
    return p;
  };
  bf16*  h0bf  = (bf16*)alloc((size_t)N * 128 * 2);
  bf16*  h1bf  = (bf16*)alloc((size_t)N * 128 * 2);
  float* aggI  = (float*)alloc((size_t)N * 128 * 4);  // later overlaid by t1g/t1r
  float* aggO  = (float*)alloc((size_t)N * 128 * 4);
  float* h2    = (float*)alloc((size_t)N * 64 * 4);
  float* W0I   = (float*)alloc(128 * 128 * 4);
  float* W0O   = (float*)alloc(128 * 128 * 4);
  float* Wcat1 = (float*)alloc(128 * 192 * 4);
  float* bi0   = (float*)alloc(128 * 4);
  float* bo0   = (float*)alloc(128 * 4);
  float* bi1   = (float*)alloc(64 * 4);
  float* bo1   = (float*)alloc(64 * 4);
  int*   cur   = (int*)alloc((size_t)2 * N * 4);
  int*   offsI = (int*)alloc((size_t)(N + 1) * 4);
  int*   offsO = (int*)alloc((size_t)(N + 1) * 4);
  int*   bcur  = (int*)alloc((size_t)2 * NBMAX * 4);
  int2*  sI    = (int2*)alloc((size_t)E * 8);
  int2*  sO    = (int2*)alloc((size_t)E * 8);
  int2*  eI    = (int2*)alloc((size_t)E * 8);
  int2*  eO    = (int2*)alloc((size_t)E * 8);
  // overlay: aggI/aggO dead after k_gemmL0; t1g (N x 128 bf16) + t1r (N x 64 bf16) fit in aggI
  bf16* t1g = (bf16*)aggI;
  bf16* t1r = t1g + (size_t)N * 128;

  (void)hipMemsetAsync(cur, 0, (size_t)2 * N * 4, stream);

  const int eb = (E + 255) / 256;
  dim3 ge(eb, 2);
  k_hist<<<ge, 256, 0, stream>>>(ei_in, ei_ou, E, cur, N);
  k_scan<<<2, 1024, 0, stream>>>(cur, offsI, offsO, bcur, N);
  dim3 gp((E + PACHUNK - 1) / PACHUNK, 2);
  k_partA<<<gp, 256, 0, stream>>>(ei_in, ew_in, ei_ou, ew_ou, E, bcur, sI, sO, NB);
  dim3 gb(NB, 2);
  k_partB<<<gb, 256, 0, stream>>>(offsI, offsO, sI, sO, eI, eO, N);
  k_wprep<<<(128 * 192 + 255) / 256, 256, 0, stream>>>(Wmi0, Wmo0, Wsh0, Wmi1, Wmo1, Wsh1, resW,
                                                       bmi0, bsi0, bmo0, bso0, bmi1, bsi1, bmo1, bso1,
                                                       W0I, W0O, Wcat1, bi0, bo0, bi1, bo1);
  k_prep0<<<(N * 128 + 255) / 256, 256, 0, stream>>>(x, pe, h0bf, N * 128);

  int ab = (N + 3) / 4;
  k_agg0<<<ab, 256, 0, stream>>>(h0bf, offsI, eI, offsO, eO, aggI, aggO, N);
  dim3 gl0((N + 63) / 64, 2);
  k_gemmL0<<<gl0, 256, 0, stream>>>(aggI, aggO, W0I, W0O, bi0, bo0, cin0, cou0, x, pe, h1bf, N);

  dim3 gl1((N + 63) / 64, 3);
  k_gemm1<<<gl1, 256, 0, stream>>>(h1bf, Wcat1, t1g, t1r, N);

  float* logp = (float*)d_out;
  float* emb  = logp + (size_t)N * 128;
  k_agg1<<<ab, 256, 0, stream>>>(t1g, t1r, offsI, eI, offsO, eO, bi1, bo1, resb, cin1, cou1,
                                 h2, emb, N);
  k_dec<<<(N + 63) / 64, 256, 0, stream>>>(h2, Wd, bd, logp, N);
}

// Round 6
// 541.928 us; speedup vs baseline: 1.0306x; 1.0306x over previous
//
#include <hip/hip_runtime.h>
#include <hip/hip_bf16.h>
#include <math.h>

typedef __hip_bfloat16  bf16;
typedef __hip_bfloat162 bf162;

#define BSZ     128   // nodes per bucket (dst >> 7)
#define NBMAX   512   // max buckets (N <= 65536)
#define PACHUNK 8192  // edges per partA block

__device__ inline float4 bf4_to_f4(uint2 v) {
  float2 lo = __bfloat1622float2(*(bf162*)&v.x);
  float2 hi = __bfloat1622float2(*(bf162*)&v.y);
  return make_float4(lo.x, lo.y, hi.x, hi.y);
}
__device__ inline uint2 f4_to_bf4(float4 v) {
  bf162 lo = __float22bfloat162_rn(make_float2(v.x, v.y));
  bf162 hi = __float22bfloat162_rn(make_float2(v.z, v.w));
  uint2 r;
  r.x = *(unsigned*)&lo;
  r.y = *(unsigned*)&hi;
  return r;
}

// ---------------- CSR build ----------------
__global__ void k_hist(const int* __restrict__ eiIn, const int* __restrict__ eiOut,
                       int E, int* __restrict__ cur, int N) {
  int e = blockIdx.x * blockDim.x + threadIdx.x;
  if (e >= E) return;
  const int* ei = blockIdx.y ? eiOut : eiIn;
  atomicAdd(cur + blockIdx.y * N + ei[E + e], 1);
}

__global__ __launch_bounds__(1024) void k_scan(int* cur, int* offsI, int* offsO,
                                               int* bucketCur, int N) {
  int* cnt  = cur + blockIdx.x * N;
  int* offs = blockIdx.x ? offsO : offsI;
  __shared__ int wsum[16];
  __shared__ int s_carry, s_total;
  const int t = threadIdx.x, lane = t & 63, wid = t >> 6;
  if (t == 0) s_carry = 0;
  __syncthreads();
  for (int base = 0; base < N; base += 1024) {
    int i = base + t;
    int v = (i < N) ? cnt[i] : 0;
    int incl = v;
    #pragma unroll
    for (int d = 1; d < 64; d <<= 1) {
      int u = __shfl_up(incl, d, 64);
      if (lane >= d) incl += u;
    }
    if (lane == 63) wsum[wid] = incl;
    __syncthreads();
    if (wid == 0) {
      int ws = (lane < 16) ? wsum[lane] : 0;
      int wi = ws;
      #pragma unroll
      for (int d = 1; d < 16; d <<= 1) {
        int u = __shfl_up(wi, d, 64);
        if (lane >= d) wi += u;
      }
      if (lane < 16) wsum[lane] = wi - ws;
      if (lane == 15) s_total = wi;
    }
    __syncthreads();
    int excl = s_carry + wsum[wid] + (incl - v);
    if (i < N) { offs[i] = excl; cnt[i] = excl; }
    __syncthreads();
    if (t == 0) s_carry += s_total;
    __syncthreads();
  }
  if (t == 0) offs[N] = s_carry;
  __syncthreads();
  int NB = (N + BSZ - 1) >> 7;
  for (int b = t; b < NB; b += 1024) bucketCur[blockIdx.x * NBMAX + b] = offs[b << 7];
}

// ---------------- partA: counting-sort edges into bucket-contiguous staging ----------------
__global__ __launch_bounds__(256) void k_partA(const int* __restrict__ eiIn, const float* __restrict__ ewIn,
                                               const int* __restrict__ eiOut, const float* __restrict__ ewOut,
                                               int E, int* __restrict__ bucketCur,
                                               int2* __restrict__ sI, int2* __restrict__ sO, int NB) {
  __shared__ int2 staged[PACHUNK];
  __shared__ int cnt[NBMAX];
  __shared__ int sb[NBMAX];
  const int t = threadIdx.x;
  const int set = blockIdx.y;
  const int*   ei = set ? eiOut : eiIn;
  const float* ew = set ? ewOut : ewIn;
  int2* stg  = set ? sO : sI;
  int*  bcur = bucketCur + set * NBMAX;
  const int base = blockIdx.x * PACHUNK;
  const int m = min(PACHUNK, E - base);
  for (int b = t; b < NB; b += 256) cnt[b] = 0;
  __syncthreads();
  #pragma unroll 4
  for (int r = 0; r < PACHUNK / 256; ++r) {
    int i = r * 256 + t;
    if (i < m) atomicAdd(&cnt[ei[E + base + i] >> 7], 1);
  }
  __syncthreads();
  if (t < 64) {
    int carry = 0;
    int nch = (NB + 63) >> 6;
    for (int c = 0; c < nch; ++c) {
      int idx = c * 64 + t;
      int v = (idx < NB) ? cnt[idx] : 0;
      int incl = v;
      #pragma unroll
      for (int d = 1; d < 64; d <<= 1) {
        int u = __shfl_up(incl, d, 64);
        if (t >= d) incl += u;
      }
      if (idx < NB) sb[idx] = carry + incl - v;
      carry += __shfl(incl, 63, 64);
    }
  }
  __syncthreads();
  for (int b = t; b < NB; b += 256) {
    int c = cnt[b];
    if (c > 0) cnt[b] = atomicAdd(&bcur[b], c) - sb[b];
  }
  __syncthreads();
  #pragma unroll 4
  for (int r = 0; r < PACHUNK / 256; ++r) {
    int i = r * 256 + t;
    if (i < m) {
      int src = ei[base + i];
      int dst = ei[E + base + i];
      float w = ew[base + i];
      int b = dst >> 7;
      int rank = atomicAdd(&sb[b], 1);
      staged[rank] = make_int2(src | ((dst & 127) << 16) | (b << 23), __float_as_int(w));
    }
  }
  __syncthreads();
  #pragma unroll 4
  for (int r = 0; r < PACHUNK / 256; ++r) {
    int j = r * 256 + t;
    if (j < m) {
      int2 p = staged[j];
      int b = ((unsigned)p.x) >> 23;
      stg[cnt[b] + j] = p;
    }
  }
}

// ---------------- partB: bucket staging -> final CSR order ----------------
__global__ __launch_bounds__(256) void k_partB(const int* __restrict__ offsI, const int* __restrict__ offsO,
                                               const int2* __restrict__ sI, const int2* __restrict__ sO,
                                               int2* __restrict__ eI, int2* __restrict__ eO, int N) {
  __shared__ int cur[BSZ];
  const int t = threadIdx.x;
  const int b = blockIdx.x;
  const int set = blockIdx.y;
  const int*  offs = set ? offsO : offsI;
  const int2* stg  = set ? sO : sI;
  int2* out = set ? eO : eI;
  int nlo = b << 7;
  int cnt = min(BSZ, N - nlo);
  if (t < cnt) cur[t] = offs[nlo + t];
  __syncthreads();
  int lo = offs[nlo], hi = offs[nlo + cnt];
  for (int i = lo + t; i < hi; i += 256) {
    int2 p = stg[i];
    int dl = (p.x >> 16) & 127;
    int pos = atomicAdd(&cur[dl], 1);
    out[pos] = make_int2(p.x & 0xffff, p.y);
  }
}

// ---------------- weight prep: Wstack0 (256x128) = [Wmi0+Ws0 ; Wmo0+Ws0]; Wcat1 (128x192) ----------------
__global__ void k_wprep(const float* __restrict__ Wmi0, const float* __restrict__ Wmo0, const float* __restrict__ Ws0,
                        const float* __restrict__ Wmi1, const float* __restrict__ Wmo1, const float* __restrict__ Ws1,
                        const float* __restrict__ resW,
                        const float* __restrict__ bmi0, const float* __restrict__ bsi0,
                        const float* __restrict__ bmo0, const float* __restrict__ bso0,
                        const float* __restrict__ bmi1, const float* __restrict__ bsi1,
                        const float* __restrict__ bmo1, const float* __restrict__ bso1,
                        float* __restrict__ Wstack0, float* __restrict__ Wcat1,
                        float* __restrict__ bi0, float* __restrict__ bo0,
                        float* __restrict__ bi1, float* __restrict__ bo1) {
  int i = blockIdx.x * blockDim.x + threadIdx.x;
  if (i < 128 * 128) {
    Wstack0[i]             = Wmi0[i] + Ws0[i];
    Wstack0[128 * 128 + i] = Wmo0[i] + Ws0[i];
  }
  if (i < 128 * 192) {
    int k = i / 192, n = i % 192;
    float v;
    if (n < 64)       v = Wmi1[k * 64 + n]       + Ws1[k * 64 + n];
    else if (n < 128) v = Wmo1[k * 64 + n - 64]  + Ws1[k * 64 + n - 64];
    else              v = resW[k * 64 + n - 128];
    Wcat1[k * 192 + n] = v;
  }
  if (i < 128) { bi0[i] = bmi0[i] + bsi0[i]; bo0[i] = bmo0[i] + bso0[i]; }
  if (i < 64)  { bi1[i] = bmi1[i] + bsi1[i]; bo1[i] = bmo1[i] + bso1[i]; }
}

// ---------------- h0 table: bf16(x + pe) ----------------
__global__ void k_prep0(const float* __restrict__ x, const float* __restrict__ pe,
                        bf16* __restrict__ h0, int total) {
  int i = blockIdx.x * blockDim.x + threadIdx.x;
  if (i < total) h0[i] = __float2bfloat16(x[i] + pe[i & 127]);
}

// ---------------- layer-0 gather: aggC = [ci*prop_in(h0) | co*prop_out(h0)] (bf16, N x 256) ----------------
// half-wave per edge, 4 cols/lane (dwordx2 bf16x4 loads); table row = 256 B.
__global__ __launch_bounds__(256) void k_agg0(const bf16* __restrict__ tb,
                                              const int* __restrict__ offsI, const int2* __restrict__ eI,
                                              const int* __restrict__ offsO, const int2* __restrict__ eO,
                                              const float* __restrict__ cin, const float* __restrict__ cou,
                                              bf16* __restrict__ aggC, int N) {
  int n = (blockIdx.x * blockDim.x + threadIdx.x) >> 6;
  int lane = threadIdx.x & 63;
  if (n >= N) return;
  const int sub = lane >> 5, sl = lane & 31;
  const char* base = (const char*)tb + sl * 8;
  float i0 = 0, i1 = 0, i2 = 0, i3 = 0, o0 = 0, o1 = 0, o2 = 0, o3 = 0;
  {
    int s0 = offsI[n], s1 = offsI[n + 1];
    int i = s0 + sub;
    for (; i + 6 < s1; i += 8) {
      int2 eA = eI[i], eB = eI[i + 2], eC = eI[i + 4], eD = eI[i + 6];
      float4 vA = bf4_to_f4(*(const uint2*)(base + ((size_t)(unsigned)eA.x << 8)));
      float4 vB = bf4_to_f4(*(const uint2*)(base + ((size_t)(unsigned)eB.x << 8)));
      float4 vC = bf4_to_f4(*(const uint2*)(base + ((size_t)(unsigned)eC.x << 8)));
      float4 vD = bf4_to_f4(*(const uint2*)(base + ((size_t)(unsigned)eD.x << 8)));
      float wA = __int_as_float(eA.y), wB = __int_as_float(eB.y);
      float wC = __int_as_float(eC.y), wD = __int_as_float(eD.y);
      i0 += wA * vA.x + wB * vB.x + wC * vC.x + wD * vD.x;
      i1 += wA * vA.y + wB * vB.y + wC * vC.y + wD * vD.y;
      i2 += wA * vA.z + wB * vB.z + wC * vC.z + wD * vD.z;
      i3 += wA * vA.w + wB * vB.w + wC * vC.w + wD * vD.w;
    }
    for (; i < s1; i += 2) {
      int2 e = eI[i];
      float4 v = bf4_to_f4(*(const uint2*)(base + ((size_t)(unsigned)e.x << 8)));
      float w = __int_as_float(e.y);
      i0 += w * v.x; i1 += w * v.y; i2 += w * v.z; i3 += w * v.w;
    }
  }
  {
    int s0 = offsO[n], s1 = offsO[n + 1];
    int i = s0 + sub;
    for (; i + 6 < s1; i += 8) {
      int2 eA = eO[i], eB = eO[i + 2], eC = eO[i + 4], eD = eO[i + 6];
      float4 vA = bf4_to_f4(*(const uint2*)(base + ((size_t)(unsigned)eA.x << 8)));
      float4 vB = bf4_to_f4(*(const uint2*)(base + ((size_t)(unsigned)eB.x << 8)));
      float4 vC = bf4_to_f4(*(const uint2*)(base + ((size_t)(unsigned)eC.x << 8)));
      float4 vD = bf4_to_f4(*(const uint2*)(base + ((size_t)(unsigned)eD.x << 8)));
      float wA = __int_as_float(eA.y), wB = __int_as_float(eB.y);
      float wC = __int_as_float(eC.y), wD = __int_as_float(eD.y);
      o0 += wA * vA.x + wB * vB.x + wC * vC.x + wD * vD.x;
      o1 += wA * vA.y + wB * vB.y + wC * vC.y + wD * vD.y;
      o2 += wA * vA.z + wB * vB.z + wC * vC.z + wD * vD.z;
      o3 += wA * vA.w + wB * vB.w + wC * vC.w + wD * vD.w;
    }
    for (; i < s1; i += 2) {
      int2 e = eO[i];
      float4 v = bf4_to_f4(*(const uint2*)(base + ((size_t)(unsigned)e.x << 8)));
      float w = __int_as_float(e.y);
      o0 += w * v.x; o1 += w * v.y; o2 += w * v.z; o3 += w * v.w;
    }
  }
  i0 += __shfl_xor(i0, 32, 64); i1 += __shfl_xor(i1, 32, 64);
  i2 += __shfl_xor(i2, 32, 64); i3 += __shfl_xor(i3, 32, 64);
  o0 += __shfl_xor(o0, 32, 64); o1 += __shfl_xor(o1, 32, 64);
  o2 += __shfl_xor(o2, 32, 64); o3 += __shfl_xor(o3, 32, 64);
  if (sub == 0) {
    float ci = cin[n], co = cou[n];
    *(uint2*)(aggC + (size_t)n * 256 + sl * 4)       = f4_to_bf4(make_float4(ci * i0, ci * i1, ci * i2, ci * i3));
    *(uint2*)(aggC + (size_t)n * 256 + 128 + sl * 4) = f4_to_bf4(make_float4(co * o0, co * o1, co * o2, co * o3));
  }
}

// ---------------- layer-0 GEMM (K=256, bf16 A) + full epilogue -> h1 (bf16) ----------------
// h1 = tanh(aggC @ Wstack0 + ci*bi + co*bo + x + pe)
__global__ __launch_bounds__(256) void k_gemmL0(const bf16* __restrict__ aggC,
                                                const float* __restrict__ Wstack0,
                                                const float* __restrict__ bi, const float* __restrict__ bo,
                                                const float* __restrict__ cin, const float* __restrict__ cou,
                                                const float* __restrict__ x, const float* __restrict__ pe,
                                                bf16* __restrict__ h1, int N) {
  __shared__ float Ast[64][65];
  __shared__ float Bs[64][68];
  const int t  = threadIdx.x;
  const int bm = blockIdx.x * 64;
  const int bn = blockIdx.y * 64;
  const int tx = t & 15, ty = t >> 4;
  const int sr = t >> 4;
  const int sc = (t & 15) * 4;
  float acc[4][4] = {};
  for (int kc = 0; kc < 256; kc += 64) {
    __syncthreads();
    #pragma unroll
    for (int j = 0; j < 4; ++j) {
      int r = j * 16 + sr;
      int gm = bm + r;
      uint2 raw = make_uint2(0u, 0u);
      if (gm < N) raw = *(const uint2*)((const char*)aggC + (size_t)gm * 512 + (kc + sc) * 2);
      float4 v = bf4_to_f4(raw);
      Ast[sc + 0][r] = v.x; Ast[sc + 1][r] = v.y;
      Ast[sc + 2][r] = v.z; Ast[sc + 3][r] = v.w;
      *(float4*)(&Bs[r][sc]) = *(const float4*)(Wstack0 + (size_t)(kc + r) * 128 + bn + sc);
    }
    __syncthreads();
    #pragma unroll 8
    for (int k = 0; k < 64; ++k) {
      float4 a = *(const float4*)(&Ast[k][ty * 4]);
      float4 b = *(const float4*)(&Bs[k][tx * 4]);
      acc[0][0] = fmaf(a.x, b.x, acc[0][0]); acc[0][1] = fmaf(a.x, b.y, acc[0][1]);
      acc[0][2] = fmaf(a.x, b.z, acc[0][2]); acc[0][3] = fmaf(a.x, b.w, acc[0][3]);
      acc[1][0] = fmaf(a.y, b.x, acc[1][0]); acc[1][1] = fmaf(a.y, b.y, acc[1][1]);
      acc[1][2] = fmaf(a.y, b.z, acc[1][2]); acc[1][3] = fmaf(a.y, b.w, acc[1][3]);
      acc[2][0] = fmaf(a.z, b.x, acc[2][0]); acc[2][1] = fmaf(a.z, b.y, acc[2][1]);
      acc[2][2] = fmaf(a.z, b.z, acc[2][2]); acc[2][3] = fmaf(a.z, b.w, acc[2][3]);
      acc[3][0] = fmaf(a.w, b.x, acc[3][0]); acc[3][1] = fmaf(a.w, b.y, acc[3][1]);
      acc[3][2] = fmaf(a.w, b.z, acc[3][2]); acc[3][3] = fmaf(a.w, b.w, acc[3][3]);
    }
  }
  const int col = bn + tx * 4;
  float4 bif = *(const float4*)(bi + col);
  float4 bof = *(const float4*)(bo + col);
  float4 pv  = *(const float4*)(pe + col);
  #pragma unroll
  for (int i = 0; i < 4; ++i) {
    int gm = bm + ty * 4 + i;
    if (gm < N) {
      float ci = cin[gm], co = cou[gm];
      float4 xv = *(const float4*)(x + (size_t)gm * 128 + col);
      float4 v;
      v.x = tanhf(acc[i][0] + ci * bif.x + co * bof.x + xv.x + pv.x);
      v.y = tanhf(acc[i][1] + ci * bif.y + co * bof.y + xv.y + pv.y);
      v.z = tanhf(acc[i][2] + ci * bif.z + co * bof.z + xv.z + pv.z);
      v.w = tanhf(acc[i][3] + ci * bif.w + co * bof.w + xv.w + pv.w);
      *(uint2*)(h1 + (size_t)gm * 128 + col) = f4_to_bf4(v);
    }
  }
}

// ---------------- layer-1 GEMM: [t1g | t1r] = h1(bf16) @ Wcat1, split outputs ----------------
__global__ __launch_bounds__(256) void k_gemm1(const bf16* __restrict__ A,
                                               const float* __restrict__ W,
                                               bf16* __restrict__ t1g, bf16* __restrict__ t1r, int N) {
  __shared__ float Ast[64][65];
  __shared__ float Bs[64][68];
  const int t  = threadIdx.x;
  const int bm = blockIdx.x * 64;
  const int bn = blockIdx.y * 64;
  const int tx = t & 15, ty = t >> 4;
  const int sr = t >> 4;
  const int sc = (t & 15) * 4;
  float acc[4][4] = {};
  for (int kc = 0; kc < 128; kc += 64) {
    __syncthreads();
    #pragma unroll
    for (int j = 0; j < 4; ++j) {
      int r = j * 16 + sr;
      int gm = bm + r;
      uint2 raw = make_uint2(0u, 0u);
      if (gm < N) raw = *(const uint2*)((const char*)A + (size_t)gm * 256 + (kc + sc) * 2);
      float4 v = bf4_to_f4(raw);
      Ast[sc + 0][r] = v.x; Ast[sc + 1][r] = v.y;
      Ast[sc + 2][r] = v.z; Ast[sc + 3][r] = v.w;
      *(float4*)(&Bs[r][sc]) = *(const float4*)(W + (size_t)(kc + r) * 192 + bn + sc);
    }
    __syncthreads();
    #pragma unroll 8
    for (int k = 0; k < 64; ++k) {
      float4 a = *(const float4*)(&Ast[k][ty * 4]);
      float4 b = *(const float4*)(&Bs[k][tx * 4]);
      acc[0][0] = fmaf(a.x, b.x, acc[0][0]); acc[0][1] = fmaf(a.x, b.y, acc[0][1]);
      acc[0][2] = fmaf(a.x, b.z, acc[0][2]); acc[0][3] = fmaf(a.x, b.w, acc[0][3]);
      acc[1][0] = fmaf(a.y, b.x, acc[1][0]); acc[1][1] = fmaf(a.y, b.y, acc[1][1]);
      acc[1][2] = fmaf(a.y, b.z, acc[1][2]); acc[1][3] = fmaf(a.y, b.w, acc[1][3]);
      acc[2][0] = fmaf(a.z, b.x, acc[2][0]); acc[2][1] = fmaf(a.z, b.y, acc[2][1]);
      acc[2][2] = fmaf(a.z, b.z, acc[2][2]); acc[2][3] = fmaf(a.z, b.w, acc[2][3]);
      acc[3][0] = fmaf(a.w, b.x, acc[3][0]); acc[3][1] = fmaf(a.w, b.y, acc[3][1]);
      acc[3][2] = fmaf(a.w, b.z, acc[3][2]); acc[3][3] = fmaf(a.w, b.w, acc[3][3]);
    }
  }
  const int col = bn + tx * 4;
  #pragma unroll
  for (int i = 0; i < 4; ++i) {
    int gm = bm + ty * 4 + i;
    if (gm < N) {
      uint2 packed = f4_to_bf4(make_float4(acc[i][0], acc[i][1], acc[i][2], acc[i][3]));
      if (col < 128) *(uint2*)(t1g + (size_t)gm * 128 + col)        = packed;
      else           *(uint2*)(t1r + (size_t)gm * 64 + (col - 128)) = packed;
    }
  }
}

// ---------------- layer-1 gather + epilogue -> h2 (fp32), emb ----------------
__global__ __launch_bounds__(256) void k_agg1(const bf16* __restrict__ t1g, const bf16* __restrict__ t1r,
                                              const int* __restrict__ offsI, const int2* __restrict__ eI,
                                              const int* __restrict__ offsO, const int2* __restrict__ eO,
                                              const float* __restrict__ bi, const float* __restrict__ bo,
                                              const float* __restrict__ resb,
                                              const float* __restrict__ cin, const float* __restrict__ cou,
                                              float* __restrict__ h2, float* __restrict__ emb, int N) {
  int n = (blockIdx.x * blockDim.x + threadIdx.x) >> 6;
  int lane = threadIdx.x & 63;
  if (n >= N) return;
  const int sub = lane >> 4;
  const int sl  = lane & 15;
  const char* baseI = (const char*)t1g + sl * 8;
  const char* baseO = baseI + 128;
  float i0 = 0, i1 = 0, i2 = 0, i3 = 0, o0 = 0, o1 = 0, o2 = 0, o3 = 0;
  {
    int s0 = offsI[n], s1 = offsI[n + 1];
    int i = s0 + sub;
    for (; i + 4 < s1; i += 8) {
      int2 eA = eI[i], eB = eI[i + 4];
      float4 vA = bf4_to_f4(*(const uint2*)(baseI + ((size_t)(unsigned)eA.x << 8)));
      float4 vB = bf4_to_f4(*(const uint2*)(baseI + ((size_t)(unsigned)eB.x << 8)));
      float wA = __int_as_float(eA.y), wB = __int_as_float(eB.y);
      i0 += wA * vA.x + wB * vB.x;
      i1 += wA * vA.y + wB * vB.y;
      i2 += wA * vA.z + wB * vB.z;
      i3 += wA * vA.w + wB * vB.w;
    }
    for (; i < s1; i += 4) {
      int2 e = eI[i];
      float4 v = bf4_to_f4(*(const uint2*)(baseI + ((size_t)(unsigned)e.x << 8)));
      float w = __int_as_float(e.y);
      i0 += w * v.x; i1 += w * v.y; i2 += w * v.z; i3 += w * v.w;
    }
  }
  {
    int s0 = offsO[n], s1 = offsO[n + 1];
    int i = s0 + sub;
    for (; i + 4 < s1; i += 8) {
      int2 eA = eO[i], eB = eO[i + 4];
      float4 vA = bf4_to_f4(*(const uint2*)(baseO + ((size_t)(unsigned)eA.x << 8)));
      float4 vB = bf4_to_f4(*(const uint2*)(baseO + ((size_t)(unsigned)eB.x << 8)));
      float wA = __int_as_float(eA.y), wB = __int_as_float(eB.y);
      o0 += wA * vA.x + wB * vB.x;
      o1 += wA * vA.y + wB * vB.y;
      o2 += wA * vA.z + wB * vB.z;
      o3 += wA * vA.w + wB * vB.w;
    }
    for (; i < s1; i += 4) {
      int2 e = eO[i];
      float4 v = bf4_to_f4(*(const uint2*)(baseO + ((size_t)(unsigned)e.x << 8)));
      float w = __int_as_float(e.y);
      o0 += w * v.x; o1 += w * v.y; o2 += w * v.z; o3 += w * v.w;
    }
  }
  i0 += __shfl_xor(i0, 32, 64); i1 += __shfl_xor(i1, 32, 64);
  i2 += __shfl_xor(i2, 32, 64); i3 += __shfl_xor(i3, 32, 64);
  o0 += __shfl_xor(o0, 32, 64); o1 += __shfl_xor(o1, 32, 64);
  o2 += __shfl_xor(o2, 32, 64); o3 += __shfl_xor(o3, 32, 64);
  i0 += __shfl_xor(i0, 16, 64); i1 += __shfl_xor(i1, 16, 64);
  i2 += __shfl_xor(i2, 16, 64); i3 += __shfl_xor(i3, 16, 64);
  o0 += __shfl_xor(o0, 16, 64); o1 += __shfl_xor(o1, 16, 64);
  o2 += __shfl_xor(o2, 16, 64); o3 += __shfl_xor(o3, 16, 64);
  if (sub == 0) {
    const int c = sl * 4;
    float ci = cin[n], co = cou[n];
    float4 bif = *(const float4*)(bi + c);
    float4 bof = *(const float4*)(bo + c);
    float4 rbf = *(const float4*)(resb + c);
    float4 rv  = bf4_to_f4(*(const uint2*)((const char*)t1r + (size_t)n * 128 + sl * 8));
    float4 v;
    v.x = tanhf(ci * (i0 + bif.x) + co * (o0 + bof.x) + rv.x + rbf.x);
    v.y = tanhf(ci * (i1 + bif.y) + co * (o1 + bof.y) + rv.y + rbf.y);
    v.z = tanhf(ci * (i2 + bif.z) + co * (o2 + bof.z) + rv.z + rbf.z);
    v.w = tanhf(ci * (i3 + bif.w) + co * (o3 + bof.w) + rv.w + rbf.w);
    *(float4*)(h2 + (size_t)n * 64 + c) = v;
    float q = v.x * v.x + v.y * v.y + v.z * v.z + v.w * v.w;
    #pragma unroll
    for (int d = 1; d < 16; d <<= 1) q += __shfl_xor(q, d, 64);
    float inv = 1.0f / (sqrtf(q) + 1e-12f);
    *(float4*)(emb + (size_t)n * 64 + c) = make_float4(v.x * inv, v.y * inv, v.z * inv, v.w * inv);
  }
}

// ---------------- decoder as register-tiled GEMM + fused log_softmax ----------------
__global__ __launch_bounds__(256) void k_dec(const float* __restrict__ h2,
                                             const float* __restrict__ Wd, const float* __restrict__ bd,
                                             float* __restrict__ logp, int N) {
  __shared__ float Ht[64][65];
  __shared__ float Bs[64][132];
  __shared__ float sb[128];
  const int t  = threadIdx.x;
  const int bm = blockIdx.x * 64;
  const int tx = t & 15, ty = t >> 4;
  const int sr = t >> 4;
  const int sc = (t & 15) * 4;
  #pragma unroll
  for (int j = 0; j < 4; ++j) {
    int r = j * 16 + sr;
    int gm = bm + r;
    float4 v = make_float4(0.f, 0.f, 0.f, 0.f);
    if (gm < N) v = *(const float4*)(h2 + (size_t)gm * 64 + sc);
    Ht[sc + 0][r] = v.x; Ht[sc + 1][r] = v.y;
    Ht[sc + 2][r] = v.z; Ht[sc + 3][r] = v.w;
    const float* wrow = Wd + (size_t)r * 128 + tx * 8;
    *(float4*)(&Bs[r][tx * 8])     = *(const float4*)(wrow);
    *(float4*)(&Bs[r][tx * 8 + 4]) = *(const float4*)(wrow + 4);
  }
  if (t < 128) sb[t] = bd[t];
  __syncthreads();
  float acc[4][8] = {};
  #pragma unroll 8
  for (int k = 0; k < 64; ++k) {
    float4 a  = *(const float4*)(&Ht[k][ty * 4]);
    float4 b0 = *(const float4*)(&Bs[k][tx * 4]);
    float4 b1 = *(const float4*)(&Bs[k][64 + tx * 4]);
    acc[0][0] = fmaf(a.x, b0.x, acc[0][0]); acc[0][1] = fmaf(a.x, b0.y, acc[0][1]);
    acc[0][2] = fmaf(a.x, b0.z, acc[0][2]); acc[0][3] = fmaf(a.x, b0.w, acc[0][3]);
    acc[0][4] = fmaf(a.x, b1.x, acc[0][4]); acc[0][5] = fmaf(a.x, b1.y, acc[0][5]);
    acc[0][6] = fmaf(a.x, b1.z, acc[0][6]); acc[0][7] = fmaf(a.x, b1.w, acc[0][7]);
    acc[1][0] = fmaf(a.y, b0.x, acc[1][0]); acc[1][1] = fmaf(a.y, b0.y, acc[1][1]);
    acc[1][2] = fmaf(a.y, b0.z, acc[1][2]); acc[1][3] = fmaf(a.y, b0.w, acc[1][3]);
    acc[1][4] = fmaf(a.y, b1.x, acc[1][4]); acc[1][5] = fmaf(a.y, b1.y, acc[1][5]);
    acc[1][6] = fmaf(a.y, b1.z, acc[1][6]); acc[1][7] = fmaf(a.y, b1.w, acc[1][7]);
    acc[2][0] = fmaf(a.z, b0.x, acc[2][0]); acc[2][1] = fmaf(a.z, b0.y, acc[2][1]);
    acc[2][2] = fmaf(a.z, b0.z, acc[2][2]); acc[2][3] = fmaf(a.z, b0.w, acc[2][3]);
    acc[2][4] = fmaf(a.z, b1.x, acc[2][4]); acc[2][5] = fmaf(a.z, b1.y, acc[2][5]);
    acc[2][6] = fmaf(a.z, b1.z, acc[2][6]); acc[2][7] = fmaf(a.z, b1.w, acc[2][7]);
    acc[3][0] = fmaf(a.w, b0.x, acc[3][0]); acc[3][1] = fmaf(a.w, b0.y, acc[3][1]);
    acc[3][2] = fmaf(a.w, b0.z, acc[3][2]); acc[3][3] = fmaf(a.w, b0.w, acc[3][3]);
    acc[3][4] = fmaf(a.w, b1.x, acc[3][4]); acc[3][5] = fmaf(a.w, b1.y, acc[3][5]);
    acc[3][6] = fmaf(a.w, b1.z, acc[3][6]); acc[3][7] = fmaf(a.w, b1.w, acc[3][7]);
  }
  float bb[8];
  #pragma unroll
  for (int j = 0; j < 4; ++j) { bb[j] = sb[tx * 4 + j]; bb[4 + j] = sb[64 + tx * 4 + j]; }
  #pragma unroll
  for (int i = 0; i < 4; ++i) {
    int gm = bm + ty * 4 + i;
    float v[8];
    #pragma unroll
    for (int j = 0; j < 8; ++j) v[j] = acc[i][j] + bb[j];
    float m = v[0];
    #pragma unroll
    for (int j = 1; j < 8; ++j) m = fmaxf(m, v[j]);
    #pragma unroll
    for (int d = 1; d < 16; d <<= 1) m = fmaxf(m, __shfl_xor(m, d, 64));
    float s = 0.f;
    #pragma unroll
    for (int j = 0; j < 8; ++j) s += __expf(v[j] - m);
    #pragma unroll
    for (int d = 1; d < 16; d <<= 1) s += __shfl_xor(s, d, 64);
    float lse = m + __logf(s);
    if (gm < N) {
      float4 o0 = make_float4(v[0] - lse, v[1] - lse, v[2] - lse, v[3] - lse);
      float4 o1 = make_float4(v[4] - lse, v[5] - lse, v[6] - lse, v[7] - lse);
      *(float4*)(logp + (size_t)gm * 128 + tx * 4)      = o0;
      *(float4*)(logp + (size_t)gm * 128 + 64 + tx * 4) = o1;
    }
  }
}

extern "C" void kernel_launch(void* const* d_in, const int* in_sizes, int n_in,
                              void* d_out, int out_size, void* d_ws, size_t ws_size,
                              hipStream_t stream) {
  const float* x     = (const float*)d_in[0];
  const int*   ei_in = (const int*)d_in[1];
  const float* ew_in = (const float*)d_in[2];
  const int*   ei_ou = (const int*)d_in[3];
  const float* ew_ou = (const float*)d_in[4];
  const float* pe    = (const float*)d_in[5];
  const float* Wmi0  = (const float*)d_in[6];
  const float* Wmo0  = (const float*)d_in[7];
  const float* Wsh0  = (const float*)d_in[8];
  const float* bmi0  = (const float*)d_in[9];
  const float* bmo0  = (const float*)d_in[10];
  const float* bsi0  = (const float*)d_in[11];
  const float* bso0  = (const float*)d_in[12];
  const float* cin0  = (const float*)d_in[13];
  const float* cou0  = (const float*)d_in[14];
  const float* Wmi1  = (const float*)d_in[15];
  const float* Wmo1  = (const float*)d_in[16];
  const float* Wsh1  = (const float*)d_in[17];
  const float* bmi1  = (const float*)d_in[18];
  const float* bmo1  = (const float*)d_in[19];
  const float* bsi1  = (const float*)d_in[20];
  const float* bso1  = (const float*)d_in[21];
  const float* cin1  = (const float*)d_in[22];
  const float* cou1  = (const float*)d_in[23];
  const float* resW  = (const float*)d_in[24];
  const float* resb  = (const float*)d_in[25];
  const float* Wd    = (const float*)d_in[26];
  const float* bd    = (const float*)d_in[27];

  const int N = in_sizes[0] / 128;
  const int E = in_sizes[2];
  const int NB = (N + BSZ - 1) >> 7;

  char* ws = (char*)d_ws;
  size_t off = 0;
  auto alloc = [&](size_t bytes) -> char* {
    off = (off + 255) & ~(size_t)255;
    char* p = ws + off;
    off += bytes;
    return p;
  };
  bf16*  h0bf  = (bf16*)alloc((size_t)N * 128 * 2);
  bf16*  h1bf  = (bf16*)alloc((size_t)N * 128 * 2);
  bf16*  aggC  = (bf16*)alloc((size_t)N * 256 * 2);   // later overlaid by t1g/t1r
  float* h2    = (float*)alloc((size_t)N * 64 * 4);
  float* Wst0  = (float*)alloc(256 * 128 * 4);
  float* Wcat1 = (float*)alloc(128 * 192 * 4);
  float* bi0   = (float*)alloc(128 * 4);
  float* bo0   = (float*)alloc(128 * 4);
  float* bi1   = (float*)alloc(64 * 4);
  float* bo1   = (float*)alloc(64 * 4);
  int*   cur   = (int*)alloc((size_t)2 * N * 4);
  int*   offsI = (int*)alloc((size_t)(N + 1) * 4);
  int*   offsO = (int*)alloc((size_t)(N + 1) * 4);
  int*   bcur  = (int*)alloc((size_t)2 * NBMAX * 4);
  int2*  sI    = (int2*)alloc((size_t)E * 8);
  int2*  sO    = (int2*)alloc((size_t)E * 8);
  int2*  eI    = (int2*)alloc((size_t)E * 8);
  int2*  eO    = (int2*)alloc((size_t)E * 8);
  // overlay: aggC dead after k_gemmL0; t1g (N x 128 bf16) + t1r (N x 64 bf16) fit inside
  bf16* t1g = aggC;
  bf16* t1r = t1g + (size_t)N * 128;

  (void)hipMemsetAsync(cur, 0, (size_t)2 * N * 4, stream);

  const int eb = (E + 255) / 256;
  dim3 ge(eb, 2);
  k_hist<<<ge, 256, 0, stream>>>(ei_in, ei_ou, E, cur, N);
  k_scan<<<2, 1024, 0, stream>>>(cur, offsI, offsO, bcur, N);
  dim3 gp((E + PACHUNK - 1) / PACHUNK, 2);
  k_partA<<<gp, 256, 0, stream>>>(ei_in, ew_in, ei_ou, ew_ou, E, bcur, sI, sO, NB);
  dim3 gb(NB, 2);
  k_partB<<<gb, 256, 0, stream>>>(offsI, offsO, sI, sO, eI, eO, N);
  k_wprep<<<(128 * 192 + 255) / 256, 256, 0, stream>>>(Wmi0, Wmo0, Wsh0, Wmi1, Wmo1, Wsh1, resW,
                                                       bmi0, bsi0, bmo0, bso0, bmi1, bsi1, bmo1, bso1,
                                                       Wst0, Wcat1, bi0, bo0, bi1, bo1);
  k_prep0<<<(N * 128 + 255) / 256, 256, 0, stream>>>(x, pe, h0bf, N * 128);

  int ab = (N + 3) / 4;
  k_agg0<<<ab, 256, 0, stream>>>(h0bf, offsI, eI, offsO, eO, cin0, cou0, aggC, N);
  dim3 gl0((N + 63) / 64, 2);
  k_gemmL0<<<gl0, 256, 0, stream>>>(aggC, Wst0, bi0, bo0, cin0, cou0, x, pe, h1bf, N);

  dim3 gl1((N + 63) / 64, 3);
  k_gemm1<<<gl1, 256, 0, stream>>>(h1bf, Wcat1, t1g, t1r, N);

  float* logp = (float*)d_out;
  float* emb  = logp + (size_t)N * 128;
  k_agg1<<<ab, 256, 0, stream>>>(t1g, t1r, offsI, eI, offsO, eO, bi1, bo1, resb, cin1, cou1,
                                 h2, emb, N);
  k_dec<<<(N + 63) / 64, 256, 0, stream>>>(h2, Wd, bd, logp, N);
}

// Round 7
// 475.971 us; speedup vs baseline: 1.1735x; 1.1386x over previous
//
#include <hip/hip_runtime.h>
#include <hip/hip_bf16.h>
#include <math.h>

typedef __hip_bfloat16  bf16;
typedef __hip_bfloat162 bf162;
typedef __attribute__((ext_vector_type(8))) short short8;   // 8 bf16 = 4 VGPRs
typedef __attribute__((ext_vector_type(4))) float floatx4;  // MFMA acc

#define BSZ     128
#define NBMAX   512
#define PACHUNK 8192

__device__ inline float4 bf4_to_f4(uint2 v) {
  float2 lo = __bfloat1622float2(*(bf162*)&v.x);
  float2 hi = __bfloat1622float2(*(bf162*)&v.y);
  return make_float4(lo.x, lo.y, hi.x, hi.y);
}
__device__ inline uint2 f4_to_bf4(float4 v) {
  bf162 lo = __float22bfloat162_rn(make_float2(v.x, v.y));
  bf162 hi = __float22bfloat162_rn(make_float2(v.z, v.w));
  uint2 r;
  r.x = *(unsigned*)&lo;
  r.y = *(unsigned*)&hi;
  return r;
}

// ---------------- CSR build ----------------
__global__ void k_hist(const int* __restrict__ eiIn, const int* __restrict__ eiOut,
                       int E, int* __restrict__ cur, int N) {
  int e = blockIdx.x * blockDim.x + threadIdx.x;
  if (e >= E) return;
  const int* ei = blockIdx.y ? eiOut : eiIn;
  atomicAdd(cur + blockIdx.y * N + ei[E + e], 1);
}

__global__ __launch_bounds__(1024) void k_scan(int* cur, int* offsI, int* offsO,
                                               int* bucketCur, int N) {
  int* cnt  = cur + blockIdx.x * N;
  int* offs = blockIdx.x ? offsO : offsI;
  __shared__ int wsum[16];
  __shared__ int s_carry, s_total;
  const int t = threadIdx.x, lane = t & 63, wid = t >> 6;
  if (t == 0) s_carry = 0;
  __syncthreads();
  for (int base = 0; base < N; base += 1024) {
    int i = base + t;
    int v = (i < N) ? cnt[i] : 0;
    int incl = v;
    #pragma unroll
    for (int d = 1; d < 64; d <<= 1) {
      int u = __shfl_up(incl, d, 64);
      if (lane >= d) incl += u;
    }
    if (lane == 63) wsum[wid] = incl;
    __syncthreads();
    if (wid == 0) {
      int ws = (lane < 16) ? wsum[lane] : 0;
      int wi = ws;
      #pragma unroll
      for (int d = 1; d < 16; d <<= 1) {
        int u = __shfl_up(wi, d, 64);
        if (lane >= d) wi += u;
      }
      if (lane < 16) wsum[lane] = wi - ws;
      if (lane == 15) s_total = wi;
    }
    __syncthreads();
    int excl = s_carry + wsum[wid] + (incl - v);
    if (i < N) { offs[i] = excl; cnt[i] = excl; }
    __syncthreads();
    if (t == 0) s_carry += s_total;
    __syncthreads();
  }
  if (t == 0) offs[N] = s_carry;
  __syncthreads();
  int NB = (N + BSZ - 1) >> 7;
  for (int b = t; b < NB; b += 1024) bucketCur[blockIdx.x * NBMAX + b] = offs[b << 7];
}

// ---------------- partA ----------------
__global__ __launch_bounds__(256) void k_partA(const int* __restrict__ eiIn, const float* __restrict__ ewIn,
                                               const int* __restrict__ eiOut, const float* __restrict__ ewOut,
                                               int E, int* __restrict__ bucketCur,
                                               int2* __restrict__ sI, int2* __restrict__ sO, int NB) {
  __shared__ int2 staged[PACHUNK];
  __shared__ int cnt[NBMAX];
  __shared__ int sb[NBMAX];
  const int t = threadIdx.x;
  const int set = blockIdx.y;
  const int*   ei = set ? eiOut : eiIn;
  const float* ew = set ? ewOut : ewIn;
  int2* stg  = set ? sO : sI;
  int*  bcur = bucketCur + set * NBMAX;
  const int base = blockIdx.x * PACHUNK;
  const int m = min(PACHUNK, E - base);
  for (int b = t; b < NB; b += 256) cnt[b] = 0;
  __syncthreads();
  #pragma unroll 4
  for (int r = 0; r < PACHUNK / 256; ++r) {
    int i = r * 256 + t;
    if (i < m) atomicAdd(&cnt[ei[E + base + i] >> 7], 1);
  }
  __syncthreads();
  if (t < 64) {
    int carry = 0;
    int nch = (NB + 63) >> 6;
    for (int c = 0; c < nch; ++c) {
      int idx = c * 64 + t;
      int v = (idx < NB) ? cnt[idx] : 0;
      int incl = v;
      #pragma unroll
      for (int d = 1; d < 64; d <<= 1) {
        int u = __shfl_up(incl, d, 64);
        if (t >= d) incl += u;
      }
      if (idx < NB) sb[idx] = carry + incl - v;
      carry += __shfl(incl, 63, 64);
    }
  }
  __syncthreads();
  for (int b = t; b < NB; b += 256) {
    int c = cnt[b];
    if (c > 0) cnt[b] = atomicAdd(&bcur[b], c) - sb[b];
  }
  __syncthreads();
  #pragma unroll 4
  for (int r = 0; r < PACHUNK / 256; ++r) {
    int i = r * 256 + t;
    if (i < m) {
      int src = ei[base + i];
      int dst = ei[E + base + i];
      float w = ew[base + i];
      int b = dst >> 7;
      int rank = atomicAdd(&sb[b], 1);
      staged[rank] = make_int2(src | ((dst & 127) << 16) | (b << 23), __float_as_int(w));
    }
  }
  __syncthreads();
  #pragma unroll 4
  for (int r = 0; r < PACHUNK / 256; ++r) {
    int j = r * 256 + t;
    if (j < m) {
      int2 p = staged[j];
      int b = ((unsigned)p.x) >> 23;
      stg[cnt[b] + j] = p;
    }
  }
}

// ---------------- partB ----------------
__global__ __launch_bounds__(256) void k_partB(const int* __restrict__ offsI, const int* __restrict__ offsO,
                                               const int2* __restrict__ sI, const int2* __restrict__ sO,
                                               int2* __restrict__ eI, int2* __restrict__ eO, int N) {
  __shared__ int cur[BSZ];
  const int t = threadIdx.x;
  const int b = blockIdx.x;
  const int set = blockIdx.y;
  const int*  offs = set ? offsO : offsI;
  const int2* stg  = set ? sO : sI;
  int2* out = set ? eO : eI;
  int nlo = b << 7;
  int cnt = min(BSZ, N - nlo);
  if (t < cnt) cur[t] = offs[nlo + t];
  __syncthreads();
  int lo = offs[nlo], hi = offs[nlo + cnt];
  for (int i = lo + t; i < hi; i += 256) {
    int2 p = stg[i];
    int dl = (p.x >> 16) & 127;
    int pos = atomicAdd(&cur[dl], 1);
    out[pos] = make_int2(p.x & 0xffff, p.y);
  }
}

// ---------------- weight prep (fp32 staging) ----------------
__global__ void k_wprep(const float* __restrict__ Wmi0, const float* __restrict__ Wmo0, const float* __restrict__ Ws0,
                        const float* __restrict__ Wmi1, const float* __restrict__ Wmo1, const float* __restrict__ Ws1,
                        const float* __restrict__ resW,
                        const float* __restrict__ bmi0, const float* __restrict__ bsi0,
                        const float* __restrict__ bmo0, const float* __restrict__ bso0,
                        const float* __restrict__ bmi1, const float* __restrict__ bsi1,
                        const float* __restrict__ bmo1, const float* __restrict__ bso1,
                        float* __restrict__ Wstack0, float* __restrict__ Wcat1,
                        float* __restrict__ bi0, float* __restrict__ bo0,
                        float* __restrict__ bi1, float* __restrict__ bo1) {
  int i = blockIdx.x * blockDim.x + threadIdx.x;
  if (i < 128 * 128) {
    Wstack0[i]             = Wmi0[i] + Ws0[i];
    Wstack0[128 * 128 + i] = Wmo0[i] + Ws0[i];
  }
  if (i < 128 * 192) {
    int k = i / 192, n = i % 192;
    float v;
    if (n < 64)       v = Wmi1[k * 64 + n]       + Ws1[k * 64 + n];
    else if (n < 128) v = Wmo1[k * 64 + n - 64]  + Ws1[k * 64 + n - 64];
    else              v = resW[k * 64 + n - 128];
    Wcat1[k * 192 + n] = v;
  }
  if (i < 128) { bi0[i] = bmi0[i] + bsi0[i]; bo0[i] = bmo0[i] + bso0[i]; }
  if (i < 64)  { bi1[i] = bmi1[i] + bsi1[i]; bo1[i] = bmo1[i] + bso1[i]; }
}

// ---------------- pack W[K x DO] fp32 -> MFMA B-fragment-linear bf16 ----------------
// frag element: P[((kt*NT + nt)*64 + lane)*8 + j] = W[kt*32 + (lane>>4)*8 + j][nt*16 + (lane&15)]
__global__ void k_pack(const float* __restrict__ W, bf16* __restrict__ P, int K, int DO) {
  int id = blockIdx.x * blockDim.x + threadIdx.x;
  int NT = DO >> 4;
  int total = (K >> 5) * NT * 64;
  if (id >= total) return;
  int lane = id & 63;
  int tile = id >> 6;
  int nt = tile % NT, kt = tile / NT;
  int col  = nt * 16 + (lane & 15);
  int krow = kt * 32 + (lane >> 4) * 8;
  bf16* dst = P + (size_t)id * 8;
  #pragma unroll
  for (int j = 0; j < 8; ++j) dst[j] = __float2bfloat16(W[(size_t)(krow + j) * DO + col]);
}

// ---------------- h0 table: bf16(x + pe) ----------------
__global__ void k_prep0(const float* __restrict__ x, const float* __restrict__ pe,
                        bf16* __restrict__ h0, int total) {
  int i = blockIdx.x * blockDim.x + threadIdx.x;
  if (i < total) h0[i] = __float2bfloat16(x[i] + pe[i & 127]);
}

// ---------------- layer-0 gather: aggC = [ci*prop_in(h0) | co*prop_out(h0)] (bf16, N x 256) ----------------
__global__ __launch_bounds__(256) void k_agg0(const bf16* __restrict__ tb,
                                              const int* __restrict__ offsI, const int2* __restrict__ eI,
                                              const int* __restrict__ offsO, const int2* __restrict__ eO,
                                              const float* __restrict__ cin, const float* __restrict__ cou,
                                              bf16* __restrict__ aggC, int N) {
  int n = (blockIdx.x * blockDim.x + threadIdx.x) >> 6;
  int lane = threadIdx.x & 63;
  if (n >= N) return;
  const int sub = lane >> 5, sl = lane & 31;
  const char* base = (const char*)tb + sl * 8;
  float i0 = 0, i1 = 0, i2 = 0, i3 = 0, o0 = 0, o1 = 0, o2 = 0, o3 = 0;
  {
    int s0 = offsI[n], s1 = offsI[n + 1];
    int i = s0 + sub;
    for (; i + 6 < s1; i += 8) {
      int2 eA = eI[i], eB = eI[i + 2], eC = eI[i + 4], eD = eI[i + 6];
      float4 vA = bf4_to_f4(*(const uint2*)(base + ((size_t)(unsigned)eA.x << 8)));
      float4 vB = bf4_to_f4(*(const uint2*)(base + ((size_t)(unsigned)eB.x << 8)));
      float4 vC = bf4_to_f4(*(const uint2*)(base + ((size_t)(unsigned)eC.x << 8)));
      float4 vD = bf4_to_f4(*(const uint2*)(base + ((size_t)(unsigned)eD.x << 8)));
      float wA = __int_as_float(eA.y), wB = __int_as_float(eB.y);
      float wC = __int_as_float(eC.y), wD = __int_as_float(eD.y);
      i0 += wA * vA.x + wB * vB.x + wC * vC.x + wD * vD.x;
      i1 += wA * vA.y + wB * vB.y + wC * vC.y + wD * vD.y;
      i2 += wA * vA.z + wB * vB.z + wC * vC.z + wD * vD.z;
      i3 += wA * vA.w + wB * vB.w + wC * vC.w + wD * vD.w;
    }
    for (; i < s1; i += 2) {
      int2 e = eI[i];
      float4 v = bf4_to_f4(*(const uint2*)(base + ((size_t)(unsigned)e.x << 8)));
      float w = __int_as_float(e.y);
      i0 += w * v.x; i1 += w * v.y; i2 += w * v.z; i3 += w * v.w;
    }
  }
  {
    int s0 = offsO[n], s1 = offsO[n + 1];
    int i = s0 + sub;
    for (; i + 6 < s1; i += 8) {
      int2 eA = eO[i], eB = eO[i + 2], eC = eO[i + 4], eD = eO[i + 6];
      float4 vA = bf4_to_f4(*(const uint2*)(base + ((size_t)(unsigned)eA.x << 8)));
      float4 vB = bf4_to_f4(*(const uint2*)(base + ((size_t)(unsigned)eB.x << 8)));
      float4 vC = bf4_to_f4(*(const uint2*)(base + ((size_t)(unsigned)eC.x << 8)));
      float4 vD = bf4_to_f4(*(const uint2*)(base + ((size_t)(unsigned)eD.x << 8)));
      float wA = __int_as_float(eA.y), wB = __int_as_float(eB.y);
      float wC = __int_as_float(eC.y), wD = __int_as_float(eD.y);
      o0 += wA * vA.x + wB * vB.x + wC * vC.x + wD * vD.x;
      o1 += wA * vA.y + wB * vB.y + wC * vC.y + wD * vD.y;
      o2 += wA * vA.z + wB * vB.z + wC * vC.z + wD * vD.z;
      o3 += wA * vA.w + wB * vB.w + wC * vC.w + wD * vD.w;
    }
    for (; i < s1; i += 2) {
      int2 e = eO[i];
      float4 v = bf4_to_f4(*(const uint2*)(base + ((size_t)(unsigned)e.x << 8)));
      float w = __int_as_float(e.y);
      o0 += w * v.x; o1 += w * v.y; o2 += w * v.z; o3 += w * v.w;
    }
  }
  i0 += __shfl_xor(i0, 32, 64); i1 += __shfl_xor(i1, 32, 64);
  i2 += __shfl_xor(i2, 32, 64); i3 += __shfl_xor(i3, 32, 64);
  o0 += __shfl_xor(o0, 32, 64); o1 += __shfl_xor(o1, 32, 64);
  o2 += __shfl_xor(o2, 32, 64); o3 += __shfl_xor(o3, 32, 64);
  if (sub == 0) {
    float ci = cin[n], co = cou[n];
    *(uint2*)(aggC + (size_t)n * 256 + sl * 4)       = f4_to_bf4(make_float4(ci * i0, ci * i1, ci * i2, ci * i3));
    *(uint2*)(aggC + (size_t)n * 256 + 128 + sl * 4) = f4_to_bf4(make_float4(co * o0, co * o1, co * o2, co * o3));
  }
}

// ---------------- layer-0 MFMA GEMM + epilogue: h1 = tanh(aggC@Wst0 + ci*bi + co*bo + h0) ----------------
// no LDS; wave = 16 rows x 128 cols; K=256 (KT=8), NT=8.
__global__ __launch_bounds__(256) void k_mf0(const bf16* __restrict__ A,      // aggC, N x 256
                                             const bf16* __restrict__ Wp,    // packed 256x128
                                             const float* __restrict__ bi, const float* __restrict__ bo,
                                             const float* __restrict__ cin, const float* __restrict__ cou,
                                             const bf16* __restrict__ h0,    // N x 128
                                             bf16* __restrict__ h1, int N) {
  const int lane = threadIdx.x & 63;
  const int quad = lane >> 4, lc = lane & 15;
  const int bmw = blockIdx.x * 64 + (threadIdx.x >> 6) * 16;
  const int rowc = min(bmw + lc, N - 1);
  const bf16* ap = A + (size_t)rowc * 256 + quad * 8;
  const short8* bp = (const short8*)Wp + lane;   // + tile*64
  floatx4 acc[8] = {};
  #pragma unroll
  for (int kt = 0; kt < 8; ++kt) {
    short8 af = *(const short8*)(ap + kt * 32);
    #pragma unroll
    for (int nt = 0; nt < 8; ++nt) {
      short8 bfr = bp[(kt * 8 + nt) * 64];
      acc[nt] = __builtin_amdgcn_mfma_f32_16x16x32_bf16(af, bfr, acc[nt], 0, 0, 0);
    }
  }
  float bif[8], bof[8];
  #pragma unroll
  for (int nt = 0; nt < 8; ++nt) {
    bif[nt] = bi[nt * 16 + lc];
    bof[nt] = bo[nt * 16 + lc];
  }
  #pragma unroll
  for (int r = 0; r < 4; ++r) {
    int gm = bmw + quad * 4 + r;
    if (gm < N) {
      float ci = cin[gm], co = cou[gm];
      #pragma unroll
      for (int nt = 0; nt < 8; ++nt) {
        int col = nt * 16 + lc;
        float v = acc[nt][r] + ci * bif[nt] + co * bof[nt]
                + __bfloat162float(h0[(size_t)gm * 128 + col]);
        h1[(size_t)gm * 128 + col] = __float2bfloat16(tanhf(v));
      }
    }
  }
}

// ---------------- layer-1 MFMA GEMM: [t1g | t1r] = h1 @ Wcat1 ; K=128 (KT=4), NT=12 ----------------
__global__ __launch_bounds__(256) void k_mf1(const bf16* __restrict__ A,     // h1, N x 128
                                             const bf16* __restrict__ Wp,   // packed 128x192
                                             bf16* __restrict__ t1g, bf16* __restrict__ t1r, int N) {
  const int lane = threadIdx.x & 63;
  const int quad = lane >> 4, lc = lane & 15;
  const int bmw = blockIdx.x * 64 + (threadIdx.x >> 6) * 16;
  const int rowc = min(bmw + lc, N - 1);
  const bf16* ap = A + (size_t)rowc * 128 + quad * 8;
  const short8* bp = (const short8*)Wp + lane;
  floatx4 acc[12] = {};
  #pragma unroll
  for (int kt = 0; kt < 4; ++kt) {
    short8 af = *(const short8*)(ap + kt * 32);
    #pragma unroll
    for (int nt = 0; nt < 12; ++nt) {
      short8 bfr = bp[(kt * 12 + nt) * 64];
      acc[nt] = __builtin_amdgcn_mfma_f32_16x16x32_bf16(af, bfr, acc[nt], 0, 0, 0);
    }
  }
  #pragma unroll
  for (int r = 0; r < 4; ++r) {
    int gm = bmw + quad * 4 + r;
    if (gm < N) {
      #pragma unroll
      for (int nt = 0; nt < 12; ++nt) {
        int col = nt * 16 + lc;
        bf16 v = __float2bfloat16(acc[nt][r]);
        if (col < 128) t1g[(size_t)gm * 128 + col]        = v;
        else           t1r[(size_t)gm * 64 + (col - 128)] = v;
      }
    }
  }
}

// ---------------- layer-1 gather + epilogue -> h2 (bf16), emb (fp32) ----------------
__global__ __launch_bounds__(256) void k_agg1(const bf16* __restrict__ t1g, const bf16* __restrict__ t1r,
                                              const int* __restrict__ offsI, const int2* __restrict__ eI,
                                              const int* __restrict__ offsO, const int2* __restrict__ eO,
                                              const float* __restrict__ bi, const float* __restrict__ bo,
                                              const float* __restrict__ resb,
                                              const float* __restrict__ cin, const float* __restrict__ cou,
                                              bf16* __restrict__ h2b, float* __restrict__ emb, int N) {
  int n = (blockIdx.x * blockDim.x + threadIdx.x) >> 6;
  int lane = threadIdx.x & 63;
  if (n >= N) return;
  const int sub = lane >> 4;
  const int sl  = lane & 15;
  const char* baseI = (const char*)t1g + sl * 8;
  const char* baseO = baseI + 128;
  float i0 = 0, i1 = 0, i2 = 0, i3 = 0, o0 = 0, o1 = 0, o2 = 0, o3 = 0;
  {
    int s0 = offsI[n], s1 = offsI[n + 1];
    int i = s0 + sub;
    for (; i + 4 < s1; i += 8) {
      int2 eA = eI[i], eB = eI[i + 4];
      float4 vA = bf4_to_f4(*(const uint2*)(baseI + ((size_t)(unsigned)eA.x << 8)));
      float4 vB = bf4_to_f4(*(const uint2*)(baseI + ((size_t)(unsigned)eB.x << 8)));
      float wA = __int_as_float(eA.y), wB = __int_as_float(eB.y);
      i0 += wA * vA.x + wB * vB.x;
      i1 += wA * vA.y + wB * vB.y;
      i2 += wA * vA.z + wB * vB.z;
      i3 += wA * vA.w + wB * vB.w;
    }
    for (; i < s1; i += 4) {
      int2 e = eI[i];
      float4 v = bf4_to_f4(*(const uint2*)(baseI + ((size_t)(unsigned)e.x << 8)));
      float w = __int_as_float(e.y);
      i0 += w * v.x; i1 += w * v.y; i2 += w * v.z; i3 += w * v.w;
    }
  }
  {
    int s0 = offsO[n], s1 = offsO[n + 1];
    int i = s0 + sub;
    for (; i + 4 < s1; i += 8) {
      int2 eA = eO[i], eB = eO[i + 4];
      float4 vA = bf4_to_f4(*(const uint2*)(baseO + ((size_t)(unsigned)eA.x << 8)));
      float4 vB = bf4_to_f4(*(const uint2*)(baseO + ((size_t)(unsigned)eB.x << 8)));
      float wA = __int_as_float(eA.y), wB = __int_as_float(eB.y);
      o0 += wA * vA.x + wB * vB.x;
      o1 += wA * vA.y + wB * vB.y;
      o2 += wA * vA.z + wB * vB.z;
      o3 += wA * vA.w + wB * vB.w;
    }
    for (; i < s1; i += 4) {
      int2 e = eO[i];
      float4 v = bf4_to_f4(*(const uint2*)(baseO + ((size_t)(unsigned)e.x << 8)));
      float w = __int_as_float(e.y);
      o0 += w * v.x; o1 += w * v.y; o2 += w * v.z; o3 += w * v.w;
    }
  }
  i0 += __shfl_xor(i0, 32, 64); i1 += __shfl_xor(i1, 32, 64);
  i2 += __shfl_xor(i2, 32, 64); i3 += __shfl_xor(i3, 32, 64);
  o0 += __shfl_xor(o0, 32, 64); o1 += __shfl_xor(o1, 32, 64);
  o2 += __shfl_xor(o2, 32, 64); o3 += __shfl_xor(o3, 32, 64);
  i0 += __shfl_xor(i0, 16, 64); i1 += __shfl_xor(i1, 16, 64);
  i2 += __shfl_xor(i2, 16, 64); i3 += __shfl_xor(i3, 16, 64);
  o0 += __shfl_xor(o0, 16, 64); o1 += __shfl_xor(o1, 16, 64);
  o2 += __shfl_xor(o2, 16, 64); o3 += __shfl_xor(o3, 16, 64);
  if (sub == 0) {
    const int c = sl * 4;
    float ci = cin[n], co = cou[n];
    float4 bif = *(const float4*)(bi + c);
    float4 bof = *(const float4*)(bo + c);
    float4 rbf = *(const float4*)(resb + c);
    float4 rv  = bf4_to_f4(*(const uint2*)((const char*)t1r + (size_t)n * 128 + sl * 8));
    float4 v;
    v.x = tanhf(ci * (i0 + bif.x) + co * (o0 + bof.x) + rv.x + rbf.x);
    v.y = tanhf(ci * (i1 + bif.y) + co * (o1 + bof.y) + rv.y + rbf.y);
    v.z = tanhf(ci * (i2 + bif.z) + co * (o2 + bof.z) + rv.z + rbf.z);
    v.w = tanhf(ci * (i3 + bif.w) + co * (o3 + bof.w) + rv.w + rbf.w);
    *(uint2*)(h2b + (size_t)n * 64 + c) = f4_to_bf4(v);
    float q = v.x * v.x + v.y * v.y + v.z * v.z + v.w * v.w;
    #pragma unroll
    for (int d = 1; d < 16; d <<= 1) q += __shfl_xor(q, d, 64);
    float inv = 1.0f / (sqrtf(q) + 1e-12f);
    *(float4*)(emb + (size_t)n * 64 + c) = make_float4(v.x * inv, v.y * inv, v.z * inv, v.w * inv);
  }
}

// ---------------- decoder MFMA GEMM + log_softmax: K=64 (KT=2), NT=8 ----------------
__global__ __launch_bounds__(256) void k_mfd(const bf16* __restrict__ A,     // h2b, N x 64
                                             const bf16* __restrict__ Wp,   // packed 64x128
                                             const float* __restrict__ bd,
                                             float* __restrict__ logp, int N) {
  const int lane = threadIdx.x & 63;
  const int quad = lane >> 4, lc = lane & 15;
  const int bmw = blockIdx.x * 64 + (threadIdx.x >> 6) * 16;
  const int rowc = min(bmw + lc, N - 1);
  const bf16* ap = A + (size_t)rowc * 64 + quad * 8;
  const short8* bp = (const short8*)Wp + lane;
  floatx4 acc[8] = {};
  #pragma unroll
  for (int kt = 0; kt < 2; ++kt) {
    short8 af = *(const short8*)(ap + kt * 32);
    #pragma unroll
    for (int nt = 0; nt < 8; ++nt) {
      short8 bfr = bp[(kt * 8 + nt) * 64];
      acc[nt] = __builtin_amdgcn_mfma_f32_16x16x32_bf16(af, bfr, acc[nt], 0, 0, 0);
    }
  }
  float bdv[8];
  #pragma unroll
  for (int nt = 0; nt < 8; ++nt) bdv[nt] = bd[nt * 16 + lc];
  #pragma unroll
  for (int r = 0; r < 4; ++r) {
    int gm = bmw + quad * 4 + r;
    float v[8];
    #pragma unroll
    for (int nt = 0; nt < 8; ++nt) v[nt] = acc[nt][r] + bdv[nt];
    float m = v[0];
    #pragma unroll
    for (int nt = 1; nt < 8; ++nt) m = fmaxf(m, v[nt]);
    #pragma unroll
    for (int d = 1; d < 16; d <<= 1) m = fmaxf(m, __shfl_xor(m, d, 64));
    float s = 0.f;
    #pragma unroll
    for (int nt = 0; nt < 8; ++nt) s += __expf(v[nt] - m);
    #pragma unroll
    for (int d = 1; d < 16; d <<= 1) s += __shfl_xor(s, d, 64);
    float lse = m + __logf(s);
    if (gm < N) {
      #pragma unroll
      for (int nt = 0; nt < 8; ++nt) logp[(size_t)gm * 128 + nt * 16 + lc] = v[nt] - lse;
    }
  }
}

extern "C" void kernel_launch(void* const* d_in, const int* in_sizes, int n_in,
                              void* d_out, int out_size, void* d_ws, size_t ws_size,
                              hipStream_t stream) {
  const float* x     = (const float*)d_in[0];
  const int*   ei_in = (const int*)d_in[1];
  const float* ew_in = (const float*)d_in[2];
  const int*   ei_ou = (const int*)d_in[3];
  const float* ew_ou = (const float*)d_in[4];
  const float* pe    = (const float*)d_in[5];
  const float* Wmi0  = (const float*)d_in[6];
  const float* Wmo0  = (const float*)d_in[7];
  const float* Wsh0  = (const float*)d_in[8];
  const float* bmi0  = (const float*)d_in[9];
  const float* bmo0  = (const float*)d_in[10];
  const float* bsi0  = (const float*)d_in[11];
  const float* bso0  = (const float*)d_in[12];
  const float* cin0  = (const float*)d_in[13];
  const float* cou0  = (const float*)d_in[14];
  const float* Wmi1  = (const float*)d_in[15];
  const float* Wmo1  = (const float*)d_in[16];
  const float* Wsh1  = (const float*)d_in[17];
  const float* bmi1  = (const float*)d_in[18];
  const float* bmo1  = (const float*)d_in[19];
  const float* bsi1  = (const float*)d_in[20];
  const float* bso1  = (const float*)d_in[21];
  const float* cin1  = (const float*)d_in[22];
  const float* cou1  = (const float*)d_in[23];
  const float* resW  = (const float*)d_in[24];
  const float* resb  = (const float*)d_in[25];
  const float* Wd    = (const float*)d_in[26];
  const float* bd    = (const float*)d_in[27];

  const int N = in_sizes[0] / 128;
  const int E = in_sizes[2];
  const int NB = (N + BSZ - 1) >> 7;

  char* ws = (char*)d_ws;
  size_t off = 0;
  auto alloc = [&](size_t bytes) -> char* {
    off = (off + 255) & ~(size_t)255;
    char* p = ws + off;
    off += bytes;
    return p;
  };
  bf16*  h0bf  = (bf16*)alloc((size_t)N * 128 * 2);
  bf16*  h1bf  = (bf16*)alloc((size_t)N * 128 * 2);
  bf16*  aggC  = (bf16*)alloc((size_t)N * 256 * 2);   // later overlaid by t1g/t1r
  bf16*  h2b   = (bf16*)alloc((size_t)N * 64 * 2);
  float* Wst0  = (float*)alloc(256 * 128 * 4);
  float* Wcat1 = (float*)alloc(128 * 192 * 4);
  bf16*  Wp0   = (bf16*)alloc(256 * 128 * 2);
  bf16*  Wp1   = (bf16*)alloc(128 * 192 * 2);
  bf16*  Wpd   = (bf16*)alloc(64 * 128 * 2);
  float* bi0   = (float*)alloc(128 * 4);
  float* bo0   = (float*)alloc(128 * 4);
  float* bi1   = (float*)alloc(64 * 4);
  float* bo1   = (float*)alloc(64 * 4);
  int*   cur   = (int*)alloc((size_t)2 * N * 4);
  int*   offsI = (int*)alloc((size_t)(N + 1) * 4);
  int*   offsO = (int*)alloc((size_t)(N + 1) * 4);
  int*   bcur  = (int*)alloc((size_t)2 * NBMAX * 4);
  int2*  sI    = (int2*)alloc((size_t)E * 8);
  int2*  sO    = (int2*)alloc((size_t)E * 8);
  int2*  eI    = (int2*)alloc((size_t)E * 8);
  int2*  eO    = (int2*)alloc((size_t)E * 8);
  bf16* t1g = aggC;                       // overlay: aggC dead after k_mf0
  bf16* t1r = t1g + (size_t)N * 128;

  (void)hipMemsetAsync(cur, 0, (size_t)2 * N * 4, stream);

  const int eb = (E + 255) / 256;
  dim3 ge(eb, 2);
  k_hist<<<ge, 256, 0, stream>>>(ei_in, ei_ou, E, cur, N);
  k_scan<<<2, 1024, 0, stream>>>(cur, offsI, offsO, bcur, N);
  dim3 gp((E + PACHUNK - 1) / PACHUNK, 2);
  k_partA<<<gp, 256, 0, stream>>>(ei_in, ew_in, ei_ou, ew_ou, E, bcur, sI, sO, NB);
  dim3 gb(NB, 2);
  k_partB<<<gb, 256, 0, stream>>>(offsI, offsO, sI, sO, eI, eO, N);
  k_wprep<<<(128 * 192 + 255) / 256, 256, 0, stream>>>(Wmi0, Wmo0, Wsh0, Wmi1, Wmo1, Wsh1, resW,
                                                       bmi0, bsi0, bmo0, bso0, bmi1, bsi1, bmo1, bso1,
                                                       Wst0, Wcat1, bi0, bo0, bi1, bo1);
  k_pack<<<(8 * 8 * 64 + 255) / 256, 256, 0, stream>>>(Wst0, Wp0, 256, 128);
  k_pack<<<(4 * 12 * 64 + 255) / 256, 256, 0, stream>>>(Wcat1, Wp1, 128, 192);
  k_pack<<<(2 * 8 * 64 + 255) / 256, 256, 0, stream>>>(Wd, Wpd, 64, 128);
  k_prep0<<<(N * 128 + 255) / 256, 256, 0, stream>>>(x, pe, h0bf, N * 128);

  int ab = (N + 3) / 4;
  int mb = (N + 63) / 64;
  k_agg0<<<ab, 256, 0, stream>>>(h0bf, offsI, eI, offsO, eO, cin0, cou0, aggC, N);
  k_mf0<<<mb, 256, 0, stream>>>(aggC, Wp0, bi0, bo0, cin0, cou0, h0bf, h1bf, N);
  k_mf1<<<mb, 256, 0, stream>>>(h1bf, Wp1, t1g, t1r, N);

  float* logp = (float*)d_out;
  float* emb  = logp + (size_t)N * 128;
  k_agg1<<<ab, 256, 0, stream>>>(t1g, t1r, offsI, eI, offsO, eO, bi1, bo1, resb, cin1, cou1,
                                 h2b, emb, N);
  k_mfd<<<mb, 256, 0, stream>>>(h2b, Wpd, bd, logp, N);
}

// Round 8
// 369.019 us; speedup vs baseline: 1.5136x; 1.2898x over previous
//
#include <hip/hip_runtime.h>
#include <hip/hip_bf16.h>
#include <math.h>

typedef __hip_bfloat16  bf16;
typedef __hip_bfloat162 bf162;
typedef __attribute__((ext_vector_type(8))) short short8;   // 8 bf16 = 4 VGPRs
typedef __attribute__((ext_vector_type(4))) float floatx4;  // MFMA acc

#define BSZ     128
#define NBMAX   512
#define PACHUNK 8192

__device__ inline float4 bf4_to_f4(uint2 v) {
  float2 lo = __bfloat1622float2(*(bf162*)&v.x);
  float2 hi = __bfloat1622float2(*(bf162*)&v.y);
  return make_float4(lo.x, lo.y, hi.x, hi.y);
}
__device__ inline uint2 f4_to_bf4(float4 v) {
  bf162 lo = __float22bfloat162_rn(make_float2(v.x, v.y));
  bf162 hi = __float22bfloat162_rn(make_float2(v.z, v.w));
  uint2 r;
  r.x = *(unsigned*)&lo;
  r.y = *(unsigned*)&hi;
  return r;
}

// ---------------- bucket histogram: LDS-privatized, 1 global atomic per bucket per block ----------------
__global__ __launch_bounds__(256) void k_bhist(const int* __restrict__ eiIn, const int* __restrict__ eiOut,
                                               int E, int* __restrict__ bcnt, int NB) {
  __shared__ int h[NBMAX];
  const int t = threadIdx.x;
  const int set = blockIdx.y;
  const int* dst = (set ? eiOut : eiIn) + E;
  for (int i = t; i < NB; i += 256) h[i] = 0;
  __syncthreads();
  const int base = blockIdx.x * PACHUNK;
  const int m = min(PACHUNK, E - base);
  #pragma unroll 4
  for (int r = 0; r < PACHUNK / 256; ++r) {
    int i = r * 256 + t;
    if (i < m) atomicAdd(&h[dst[base + i] >> 7], 1);
  }
  __syncthreads();
  for (int i = t; i < NB; i += 256) {
    int c = h[i];
    if (c) atomicAdd(&bcnt[set * NBMAX + i], c);
  }
}

// ---------------- bucket scan: exclusive prefix over NB buckets -> BO, bcur ----------------
__global__ __launch_bounds__(64) void k_bscan(const int* __restrict__ bcnt,
                                              int* __restrict__ BO, int* __restrict__ bcur, int NB) {
  const int set = blockIdx.x;
  const int t = threadIdx.x;
  int carry = 0;
  for (int base = 0; base < NB; base += 64) {
    int idx = base + t;
    int v = (idx < NB) ? bcnt[set * NBMAX + idx] : 0;
    int incl = v;
    #pragma unroll
    for (int d = 1; d < 64; d <<= 1) {
      int u = __shfl_up(incl, d, 64);
      if (t >= d) incl += u;
    }
    if (idx < NB) {
      int e = carry + incl - v;
      BO[set * NBMAX + idx]   = e;
      bcur[set * NBMAX + idx] = e;
    }
    carry += __shfl(incl, 63, 64);
  }
}

// ---------------- partA: counting-sort edges into bucket-contiguous staging ----------------
__global__ __launch_bounds__(256) void k_partA(const int* __restrict__ eiIn, const float* __restrict__ ewIn,
                                               const int* __restrict__ eiOut, const float* __restrict__ ewOut,
                                               int E, int* __restrict__ bucketCur,
                                               int2* __restrict__ sI, int2* __restrict__ sO, int NB) {
  __shared__ int2 staged[PACHUNK];
  __shared__ int cnt[NBMAX];
  __shared__ int sb[NBMAX];
  const int t = threadIdx.x;
  const int set = blockIdx.y;
  const int*   ei = set ? eiOut : eiIn;
  const float* ew = set ? ewOut : ewIn;
  int2* stg  = set ? sO : sI;
  int*  bcur = bucketCur + set * NBMAX;
  const int base = blockIdx.x * PACHUNK;
  const int m = min(PACHUNK, E - base);
  for (int b = t; b < NB; b += 256) cnt[b] = 0;
  __syncthreads();
  #pragma unroll 4
  for (int r = 0; r < PACHUNK / 256; ++r) {
    int i = r * 256 + t;
    if (i < m) atomicAdd(&cnt[ei[E + base + i] >> 7], 1);
  }
  __syncthreads();
  if (t < 64) {
    int carry = 0;
    int nch = (NB + 63) >> 6;
    for (int c = 0; c < nch; ++c) {
      int idx = c * 64 + t;
      int v = (idx < NB) ? cnt[idx] : 0;
      int incl = v;
      #pragma unroll
      for (int d = 1; d < 64; d <<= 1) {
        int u = __shfl_up(incl, d, 64);
        if (t >= d) incl += u;
      }
      if (idx < NB) sb[idx] = carry + incl - v;
      carry += __shfl(incl, 63, 64);
    }
  }
  __syncthreads();
  for (int b = t; b < NB; b += 256) {
    int c = cnt[b];
    if (c > 0) cnt[b] = atomicAdd(&bcur[b], c) - sb[b];
  }
  __syncthreads();
  #pragma unroll 4
  for (int r = 0; r < PACHUNK / 256; ++r) {
    int i = r * 256 + t;
    if (i < m) {
      int src = ei[base + i];
      int dst = ei[E + base + i];
      float w = ew[base + i];
      int b = dst >> 7;
      int rank = atomicAdd(&sb[b], 1);
      staged[rank] = make_int2(src | ((dst & 127) << 16) | (b << 23), __float_as_int(w));
    }
  }
  __syncthreads();
  #pragma unroll 4
  for (int r = 0; r < PACHUNK / 256; ++r) {
    int j = r * 256 + t;
    if (j < m) {
      int2 p = staged[j];
      int b = ((unsigned)p.x) >> 23;
      stg[cnt[b] + j] = p;
    }
  }
}

// ---------------- partB: bucket staging -> per-node offsets (LDS scan) + final CSR order ----------------
__global__ __launch_bounds__(256) void k_partB(const int* __restrict__ BO, const int* __restrict__ bcur,
                                               const int2* __restrict__ sI, const int2* __restrict__ sO,
                                               int2* __restrict__ eI, int2* __restrict__ eO,
                                               int* __restrict__ offsI, int* __restrict__ offsO, int N) {
  __shared__ int cnt[BSZ];
  __shared__ int excl[BSZ];
  __shared__ int cur[BSZ];
  const int t = threadIdx.x;
  const int b = blockIdx.x;
  const int set = blockIdx.y;
  const int2* stg = set ? sO : sI;
  int2* out = set ? eO : eI;
  int*  offs = set ? offsO : offsI;
  const int nlo = b << 7;
  const int nodes = min(BSZ, N - nlo);
  const int lo = BO[set * NBMAX + b];
  const int hi = bcur[set * NBMAX + b];   // post-partA cursor == bucket end
  if (t < BSZ) cnt[t] = 0;
  __syncthreads();
  for (int i = lo + t; i < hi; i += 256) atomicAdd(&cnt[(stg[i].x >> 16) & 127], 1);
  __syncthreads();
  if (t < 64) {
    int v0 = cnt[t];
    int i0 = v0;
    #pragma unroll
    for (int d = 1; d < 64; d <<= 1) { int u = __shfl_up(i0, d, 64); if (t >= d) i0 += u; }
    int v1 = cnt[64 + t];
    int i1 = v1;
    #pragma unroll
    for (int d = 1; d < 64; d <<= 1) { int u = __shfl_up(i1, d, 64); if (t >= d) i1 += u; }
    int tot0 = __shfl(i0, 63, 64);
    excl[t]      = i0 - v0;
    excl[64 + t] = tot0 + i1 - v1;
  }
  __syncthreads();
  if (t < BSZ) cur[t] = lo + excl[t];
  if (t < nodes) offs[nlo + t] = lo + excl[t];
  if (b == gridDim.x - 1 && t == 0) offs[N] = hi;
  __syncthreads();
  for (int i = lo + t; i < hi; i += 256) {
    int2 p = stg[i];
    int dl = (p.x >> 16) & 127;
    int pos = atomicAdd(&cur[dl], 1);
    out[pos] = make_int2(p.x & 0xffff, p.y);
  }
}

// ---------------- weight prep (fp32 staging) ----------------
__global__ void k_wprep(const float* __restrict__ Wmi0, const float* __restrict__ Wmo0, const float* __restrict__ Ws0,
                        const float* __restrict__ Wmi1, const float* __restrict__ Wmo1, const float* __restrict__ Ws1,
                        const float* __restrict__ resW,
                        const float* __restrict__ bmi0, const float* __restrict__ bsi0,
                        const float* __restrict__ bmo0, const float* __restrict__ bso0,
                        const float* __restrict__ bmi1, const float* __restrict__ bsi1,
                        const float* __restrict__ bmo1, const float* __restrict__ bso1,
                        float* __restrict__ Wstack0, float* __restrict__ Wcat1,
                        float* __restrict__ bi0, float* __restrict__ bo0,
                        float* __restrict__ bi1, float* __restrict__ bo1) {
  int i = blockIdx.x * blockDim.x + threadIdx.x;
  if (i < 128 * 128) {
    Wstack0[i]             = Wmi0[i] + Ws0[i];
    Wstack0[128 * 128 + i] = Wmo0[i] + Ws0[i];
  }
  if (i < 128 * 192) {
    int k = i / 192, n = i % 192;
    float v;
    if (n < 64)       v = Wmi1[k * 64 + n]       + Ws1[k * 64 + n];
    else if (n < 128) v = Wmo1[k * 64 + n - 64]  + Ws1[k * 64 + n - 64];
    else              v = resW[k * 64 + n - 128];
    Wcat1[k * 192 + n] = v;
  }
  if (i < 128) { bi0[i] = bmi0[i] + bsi0[i]; bo0[i] = bmo0[i] + bso0[i]; }
  if (i < 64)  { bi1[i] = bmi1[i] + bsi1[i]; bo1[i] = bmo1[i] + bso1[i]; }
}

// ---------------- pack all weights -> MFMA B-fragment-linear bf16 (one dispatch) ----------------
__device__ inline void pack_one(const float* __restrict__ W, bf16* __restrict__ P,
                                int id, int NT, int DO) {
  int lane = id & 63;
  int tile = id >> 6;
  int nt = tile % NT, kt = tile / NT;
  int col  = nt * 16 + (lane & 15);
  int krow = kt * 32 + (lane >> 4) * 8;
  bf16* dst = P + (size_t)id * 8;
  #pragma unroll
  for (int j = 0; j < 8; ++j) dst[j] = __float2bfloat16(W[(size_t)(krow + j) * DO + col]);
}
__global__ void k_packall(const float* __restrict__ W0, const float* __restrict__ W1,
                          const float* __restrict__ Wd,
                          bf16* __restrict__ P0, bf16* __restrict__ P1, bf16* __restrict__ Pd) {
  int id = blockIdx.x * blockDim.x + threadIdx.x;
  const int T0 = 8 * 8 * 64;    // 256x128
  const int T1 = 4 * 12 * 64;   // 128x192
  const int Td = 2 * 8 * 64;    // 64x128
  if (id < T0)                pack_one(W0, P0, id, 8, 128);
  else if (id < T0 + T1)      pack_one(W1, P1, id - T0, 12, 192);
  else if (id < T0 + T1 + Td) pack_one(Wd, Pd, id - T0 - T1, 8, 128);
}

// ---------------- h0 table: bf16(x + pe) ----------------
__global__ void k_prep0(const float* __restrict__ x, const float* __restrict__ pe,
                        bf16* __restrict__ h0, int total) {
  int i = blockIdx.x * blockDim.x + threadIdx.x;
  if (i < total) h0[i] = __float2bfloat16(x[i] + pe[i & 127]);
}

// ---------------- layer-0 gather: aggC = [ci*prop_in(h0) | co*prop_out(h0)] (bf16, N x 256) ----------------
__global__ __launch_bounds__(256) void k_agg0(const bf16* __restrict__ tb,
                                              const int* __restrict__ offsI, const int2* __restrict__ eI,
                                              const int* __restrict__ offsO, const int2* __restrict__ eO,
                                              const float* __restrict__ cin, const float* __restrict__ cou,
                                              bf16* __restrict__ aggC, int N) {
  int n = (blockIdx.x * blockDim.x + threadIdx.x) >> 6;
  int lane = threadIdx.x & 63;
  if (n >= N) return;
  const int sub = lane >> 5, sl = lane & 31;
  const char* base = (const char*)tb + sl * 8;
  float i0 = 0, i1 = 0, i2 = 0, i3 = 0, o0 = 0, o1 = 0, o2 = 0, o3 = 0;
  {
    int s0 = offsI[n], s1 = offsI[n + 1];
    int i = s0 + sub;
    for (; i + 6 < s1; i += 8) {
      int2 eA = eI[i], eB = eI[i + 2], eC = eI[i + 4], eD = eI[i + 6];
      float4 vA = bf4_to_f4(*(const uint2*)(base + ((size_t)(unsigned)eA.x << 8)));
      float4 vB = bf4_to_f4(*(const uint2*)(base + ((size_t)(unsigned)eB.x << 8)));
      float4 vC = bf4_to_f4(*(const uint2*)(base + ((size_t)(unsigned)eC.x << 8)));
      float4 vD = bf4_to_f4(*(const uint2*)(base + ((size_t)(unsigned)eD.x << 8)));
      float wA = __int_as_float(eA.y), wB = __int_as_float(eB.y);
      float wC = __int_as_float(eC.y), wD = __int_as_float(eD.y);
      i0 += wA * vA.x + wB * vB.x + wC * vC.x + wD * vD.x;
      i1 += wA * vA.y + wB * vB.y + wC * vC.y + wD * vD.y;
      i2 += wA * vA.z + wB * vB.z + wC * vC.z + wD * vD.z;
      i3 += wA * vA.w + wB * vB.w + wC * vC.w + wD * vD.w;
    }
    for (; i < s1; i += 2) {
      int2 e = eI[i];
      float4 v = bf4_to_f4(*(const uint2*)(base + ((size_t)(unsigned)e.x << 8)));
      float w = __int_as_float(e.y);
      i0 += w * v.x; i1 += w * v.y; i2 += w * v.z; i3 += w * v.w;
    }
  }
  {
    int s0 = offsO[n], s1 = offsO[n + 1];
    int i = s0 + sub;
    for (; i + 6 < s1; i += 8) {
      int2 eA = eO[i], eB = eO[i + 2], eC = eO[i + 4], eD = eO[i + 6];
      float4 vA = bf4_to_f4(*(const uint2*)(base + ((size_t)(unsigned)eA.x << 8)));
      float4 vB = bf4_to_f4(*(const uint2*)(base + ((size_t)(unsigned)eB.x << 8)));
      float4 vC = bf4_to_f4(*(const uint2*)(base + ((size_t)(unsigned)eC.x << 8)));
      float4 vD = bf4_to_f4(*(const uint2*)(base + ((size_t)(unsigned)eD.x << 8)));
      float wA = __int_as_float(eA.y), wB = __int_as_float(eB.y);
      float wC = __int_as_float(eC.y), wD = __int_as_float(eD.y);
      o0 += wA * vA.x + wB * vB.x + wC * vC.x + wD * vD.x;
      o1 += wA * vA.y + wB * vB.y + wC * vC.y + wD * vD.y;
      o2 += wA * vA.z + wB * vB.z + wC * vC.z + wD * vD.z;
      o3 += wA * vA.w + wB * vB.w + wC * vC.w + wD * vD.w;
    }
    for (; i < s1; i += 2) {
      int2 e = eO[i];
      float4 v = bf4_to_f4(*(const uint2*)(base + ((size_t)(unsigned)e.x << 8)));
      float w = __int_as_float(e.y);
      o0 += w * v.x; o1 += w * v.y; o2 += w * v.z; o3 += w * v.w;
    }
  }
  i0 += __shfl_xor(i0, 32, 64); i1 += __shfl_xor(i1, 32, 64);
  i2 += __shfl_xor(i2, 32, 64); i3 += __shfl_xor(i3, 32, 64);
  o0 += __shfl_xor(o0, 32, 64); o1 += __shfl_xor(o1, 32, 64);
  o2 += __shfl_xor(o2, 32, 64); o3 += __shfl_xor(o3, 32, 64);
  if (sub == 0) {
    float ci = cin[n], co = cou[n];
    *(uint2*)(aggC + (size_t)n * 256 + sl * 4)       = f4_to_bf4(make_float4(ci * i0, ci * i1, ci * i2, ci * i3));
    *(uint2*)(aggC + (size_t)n * 256 + 128 + sl * 4) = f4_to_bf4(make_float4(co * o0, co * o1, co * o2, co * o3));
  }
}

// ---------------- layer-0 MFMA GEMM + epilogue: h1 = tanh(aggC@Wst0 + ci*bi + co*bo + h0) ----------------
__global__ __launch_bounds__(256) void k_mf0(const bf16* __restrict__ A,
                                             const bf16* __restrict__ Wp,
                                             const float* __restrict__ bi, const float* __restrict__ bo,
                                             const float* __restrict__ cin, const float* __restrict__ cou,
                                             const bf16* __restrict__ h0,
                                             bf16* __restrict__ h1, int N) {
  const int lane = threadIdx.x & 63;
  const int quad = lane >> 4, lc = lane & 15;
  const int bmw = blockIdx.x * 64 + (threadIdx.x >> 6) * 16;
  const int rowc = min(bmw + lc, N - 1);
  const bf16* ap = A + (size_t)rowc * 256 + quad * 8;
  const short8* bp = (const short8*)Wp + lane;
  floatx4 acc[8] = {};
  #pragma unroll
  for (int kt = 0; kt < 8; ++kt) {
    short8 af = *(const short8*)(ap + kt * 32);
    #pragma unroll
    for (int nt = 0; nt < 8; ++nt) {
      short8 bfr = bp[(kt * 8 + nt) * 64];
      acc[nt] = __builtin_amdgcn_mfma_f32_16x16x32_bf16(af, bfr, acc[nt], 0, 0, 0);
    }
  }
  float bif[8], bof[8];
  #pragma unroll
  for (int nt = 0; nt < 8; ++nt) {
    bif[nt] = bi[nt * 16 + lc];
    bof[nt] = bo[nt * 16 + lc];
  }
  #pragma unroll
  for (int r = 0; r < 4; ++r) {
    int gm = bmw + quad * 4 + r;
    if (gm < N) {
      float ci = cin[gm], co = cou[gm];
      #pragma unroll
      for (int nt = 0; nt < 8; ++nt) {
        int col = nt * 16 + lc;
        float v = acc[nt][r] + ci * bif[nt] + co * bof[nt]
                + __bfloat162float(h0[(size_t)gm * 128 + col]);
        h1[(size_t)gm * 128 + col] = __float2bfloat16(tanhf(v));
      }
    }
  }
}

// ---------------- layer-1 MFMA GEMM: [t1g | t1r] = h1 @ Wcat1 ----------------
__global__ __launch_bounds__(256) void k_mf1(const bf16* __restrict__ A,
                                             const bf16* __restrict__ Wp,
                                             bf16* __restrict__ t1g, bf16* __restrict__ t1r, int N) {
  const int lane = threadIdx.x & 63;
  const int quad = lane >> 4, lc = lane & 15;
  const int bmw = blockIdx.x * 64 + (threadIdx.x >> 6) * 16;
  const int rowc = min(bmw + lc, N - 1);
  const bf16* ap = A + (size_t)rowc * 128 + quad * 8;
  const short8* bp = (const short8*)Wp + lane;
  floatx4 acc[12] = {};
  #pragma unroll
  for (int kt = 0; kt < 4; ++kt) {
    short8 af = *(const short8*)(ap + kt * 32);
    #pragma unroll
    for (int nt = 0; nt < 12; ++nt) {
      short8 bfr = bp[(kt * 12 + nt) * 64];
      acc[nt] = __builtin_amdgcn_mfma_f32_16x16x32_bf16(af, bfr, acc[nt], 0, 0, 0);
    }
  }
  #pragma unroll
  for (int r = 0; r < 4; ++r) {
    int gm = bmw + quad * 4 + r;
    if (gm < N) {
      #pragma unroll
      for (int nt = 0; nt < 12; ++nt) {
        int col = nt * 16 + lc;
        bf16 v = __float2bfloat16(acc[nt][r]);
        if (col < 128) t1g[(size_t)gm * 128 + col]        = v;
        else           t1r[(size_t)gm * 64 + (col - 128)] = v;
      }
    }
  }
}

// ---------------- layer-1 gather + epilogue -> h2 (bf16), emb (fp32) ----------------
__global__ __launch_bounds__(256) void k_agg1(const bf16* __restrict__ t1g, const bf16* __restrict__ t1r,
                                              const int* __restrict__ offsI, const int2* __restrict__ eI,
                                              const int* __restrict__ offsO, const int2* __restrict__ eO,
                                              const float* __restrict__ bi, const float* __restrict__ bo,
                                              const float* __restrict__ resb,
                                              const float* __restrict__ cin, const float* __restrict__ cou,
                                              bf16* __restrict__ h2b, float* __restrict__ emb, int N) {
  int n = (blockIdx.x * blockDim.x + threadIdx.x) >> 6;
  int lane = threadIdx.x & 63;
  if (n >= N) return;
  const int sub = lane >> 4;
  const int sl  = lane & 15;
  const char* baseI = (const char*)t1g + sl * 8;
  const char* baseO = baseI + 128;
  float i0 = 0, i1 = 0, i2 = 0, i3 = 0, o0 = 0, o1 = 0, o2 = 0, o3 = 0;
  {
    int s0 = offsI[n], s1 = offsI[n + 1];
    int i = s0 + sub;
    for (; i + 4 < s1; i += 8) {
      int2 eA = eI[i], eB = eI[i + 4];
      float4 vA = bf4_to_f4(*(const uint2*)(baseI + ((size_t)(unsigned)eA.x << 8)));
      float4 vB = bf4_to_f4(*(const uint2*)(baseI + ((size_t)(unsigned)eB.x << 8)));
      float wA = __int_as_float(eA.y), wB = __int_as_float(eB.y);
      i0 += wA * vA.x + wB * vB.x;
      i1 += wA * vA.y + wB * vB.y;
      i2 += wA * vA.z + wB * vB.z;
      i3 += wA * vA.w + wB * vB.w;
    }
    for (; i < s1; i += 4) {
      int2 e = eI[i];
      float4 v = bf4_to_f4(*(const uint2*)(baseI + ((size_t)(unsigned)e.x << 8)));
      float w = __int_as_float(e.y);
      i0 += w * v.x; i1 += w * v.y; i2 += w * v.z; i3 += w * v.w;
    }
  }
  {
    int s0 = offsO[n], s1 = offsO[n + 1];
    int i = s0 + sub;
    for (; i + 4 < s1; i += 8) {
      int2 eA = eO[i], eB = eO[i + 4];
      float4 vA = bf4_to_f4(*(const uint2*)(baseO + ((size_t)(unsigned)eA.x << 8)));
      float4 vB = bf4_to_f4(*(const uint2*)(baseO + ((size_t)(unsigned)eB.x << 8)));
      float wA = __int_as_float(eA.y), wB = __int_as_float(eB.y);
      o0 += wA * vA.x + wB * vB.x;
      o1 += wA * vA.y + wB * vB.y;
      o2 += wA * vA.z + wB * vB.z;
      o3 += wA * vA.w + wB * vB.w;
    }
    for (; i < s1; i += 4) {
      int2 e = eO[i];
      float4 v = bf4_to_f4(*(const uint2*)(baseO + ((size_t)(unsigned)e.x << 8)));
      float w = __int_as_float(e.y);
      o0 += w * v.x; o1 += w * v.y; o2 += w * v.z; o3 += w * v.w;
    }
  }
  i0 += __shfl_xor(i0, 32, 64); i1 += __shfl_xor(i1, 32, 64);
  i2 += __shfl_xor(i2, 32, 64); i3 += __shfl_xor(i3, 32, 64);
  o0 += __shfl_xor(o0, 32, 64); o1 += __shfl_xor(o1, 32, 64);
  o2 += __shfl_xor(o2, 32, 64); o3 += __shfl_xor(o3, 32, 64);
  i0 += __shfl_xor(i0, 16, 64); i1 += __shfl_xor(i1, 16, 64);
  i2 += __shfl_xor(i2, 16, 64); i3 += __shfl_xor(i3, 16, 64);
  o0 += __shfl_xor(o0, 16, 64); o1 += __shfl_xor(o1, 16, 64);
  o2 += __shfl_xor(o2, 16, 64); o3 += __shfl_xor(o3, 16, 64);
  if (sub == 0) {
    const int c = sl * 4;
    float ci = cin[n], co = cou[n];
    float4 bif = *(const float4*)(bi + c);
    float4 bof = *(const float4*)(bo + c);
    float4 rbf = *(const float4*)(resb + c);
    float4 rv  = bf4_to_f4(*(const uint2*)((const char*)t1r + (size_t)n * 128 + sl * 8));
    float4 v;
    v.x = tanhf(ci * (i0 + bif.x) + co * (o0 + bof.x) + rv.x + rbf.x);
    v.y = tanhf(ci * (i1 + bif.y) + co * (o1 + bof.y) + rv.y + rbf.y);
    v.z = tanhf(ci * (i2 + bif.z) + co * (o2 + bof.z) + rv.z + rbf.z);
    v.w = tanhf(ci * (i3 + bif.w) + co * (o3 + bof.w) + rv.w + rbf.w);
    *(uint2*)(h2b + (size_t)n * 64 + c) = f4_to_bf4(v);
    float q = v.x * v.x + v.y * v.y + v.z * v.z + v.w * v.w;
    #pragma unroll
    for (int d = 1; d < 16; d <<= 1) q += __shfl_xor(q, d, 64);
    float inv = 1.0f / (sqrtf(q) + 1e-12f);
    *(float4*)(emb + (size_t)n * 64 + c) = make_float4(v.x * inv, v.y * inv, v.z * inv, v.w * inv);
  }
}

// ---------------- decoder MFMA GEMM + log_softmax ----------------
__global__ __launch_bounds__(256) void k_mfd(const bf16* __restrict__ A,
                                             const bf16* __restrict__ Wp,
                                             const float* __restrict__ bd,
                                             float* __restrict__ logp, int N) {
  const int lane = threadIdx.x & 63;
  const int quad = lane >> 4, lc = lane & 15;
  const int bmw = blockIdx.x * 64 + (threadIdx.x >> 6) * 16;
  const int rowc = min(bmw + lc, N - 1);
  const bf16* ap = A + (size_t)rowc * 64 + quad * 8;
  const short8* bp = (const short8*)Wp + lane;
  floatx4 acc[8] = {};
  #pragma unroll
  for (int kt = 0; kt < 2; ++kt) {
    short8 af = *(const short8*)(ap + kt * 32);
    #pragma unroll
    for (int nt = 0; nt < 8; ++nt) {
      short8 bfr = bp[(kt * 8 + nt) * 64];
      acc[nt] = __builtin_amdgcn_mfma_f32_16x16x32_bf16(af, bfr, acc[nt], 0, 0, 0);
    }
  }
  float bdv[8];
  #pragma unroll
  for (int nt = 0; nt < 8; ++nt) bdv[nt] = bd[nt * 16 + lc];
  #pragma unroll
  for (int r = 0; r < 4; ++r) {
    int gm = bmw + quad * 4 + r;
    float v[8];
    #pragma unroll
    for (int nt = 0; nt < 8; ++nt) v[nt] = acc[nt][r] + bdv[nt];
    float m = v[0];
    #pragma unroll
    for (int nt = 1; nt < 8; ++nt) m = fmaxf(m, v[nt]);
    #pragma unroll
    for (int d = 1; d < 16; d <<= 1) m = fmaxf(m, __shfl_xor(m, d, 64));
    float s = 0.f;
    #pragma unroll
    for (int nt = 0; nt < 8; ++nt) s += __expf(v[nt] - m);
    #pragma unroll
    for (int d = 1; d < 16; d <<= 1) s += __shfl_xor(s, d, 64);
    float lse = m + __logf(s);
    if (gm < N) {
      #pragma unroll
      for (int nt = 0; nt < 8; ++nt) logp[(size_t)gm * 128 + nt * 16 + lc] = v[nt] - lse;
    }
  }
}

extern "C" void kernel_launch(void* const* d_in, const int* in_sizes, int n_in,
                              void* d_out, int out_size, void* d_ws, size_t ws_size,
                              hipStream_t stream) {
  const float* x     = (const float*)d_in[0];
  const int*   ei_in = (const int*)d_in[1];
  const float* ew_in = (const float*)d_in[2];
  const int*   ei_ou = (const int*)d_in[3];
  const float* ew_ou = (const float*)d_in[4];
  const float* pe    = (const float*)d_in[5];
  const float* Wmi0  = (const float*)d_in[6];
  const float* Wmo0  = (const float*)d_in[7];
  const float* Wsh0  = (const float*)d_in[8];
  const float* bmi0  = (const float*)d_in[9];
  const float* bmo0  = (const float*)d_in[10];
  const float* bsi0  = (const float*)d_in[11];
  const float* bso0  = (const float*)d_in[12];
  const float* cin0  = (const float*)d_in[13];
  const float* cou0  = (const float*)d_in[14];
  const float* Wmi1  = (const float*)d_in[15];
  const float* Wmo1  = (const float*)d_in[16];
  const float* Wsh1  = (const float*)d_in[17];
  const float* bmi1  = (const float*)d_in[18];
  const float* bmo1  = (const float*)d_in[19];
  const float* bsi1  = (const float*)d_in[20];
  const float* bso1  = (const float*)d_in[21];
  const float* cin1  = (const float*)d_in[22];
  const float* cou1  = (const float*)d_in[23];
  const float* resW  = (const float*)d_in[24];
  const float* resb  = (const float*)d_in[25];
  const float* Wd    = (const float*)d_in[26];
  const float* bd    = (const float*)d_in[27];

  const int N = in_sizes[0] / 128;
  const int E = in_sizes[2];
  const int NB = (N + BSZ - 1) >> 7;

  char* ws = (char*)d_ws;
  size_t off = 0;
  auto alloc = [&](size_t bytes) -> char* {
    off = (off + 255) & ~(size_t)255;
    char* p = ws + off;
    off += bytes;
    return p;
  };
  bf16*  h0bf  = (bf16*)alloc((size_t)N * 128 * 2);
  bf16*  h1bf  = (bf16*)alloc((size_t)N * 128 * 2);
  bf16*  aggC  = (bf16*)alloc((size_t)N * 256 * 2);   // later overlaid by t1g/t1r
  bf16*  h2b   = (bf16*)alloc((size_t)N * 64 * 2);
  float* Wst0  = (float*)alloc(256 * 128 * 4);
  float* Wcat1 = (float*)alloc(128 * 192 * 4);
  bf16*  Wp0   = (bf16*)alloc(256 * 128 * 2);
  bf16*  Wp1   = (bf16*)alloc(128 * 192 * 2);
  bf16*  Wpd   = (bf16*)alloc(64 * 128 * 2);
  float* bi0   = (float*)alloc(128 * 4);
  float* bo0   = (float*)alloc(128 * 4);
  float* bi1   = (float*)alloc(64 * 4);
  float* bo1   = (float*)alloc(64 * 4);
  int*   bcnt  = (int*)alloc((size_t)2 * NBMAX * 4);
  int*   BO    = (int*)alloc((size_t)2 * NBMAX * 4);
  int*   bcur  = (int*)alloc((size_t)2 * NBMAX * 4);
  int*   offsI = (int*)alloc((size_t)(N + 1) * 4);
  int*   offsO = (int*)alloc((size_t)(N + 1) * 4);
  int2*  sI    = (int2*)alloc((size_t)E * 8);
  int2*  sO    = (int2*)alloc((size_t)E * 8);
  int2*  eI    = (int2*)alloc((size_t)E * 8);
  int2*  eO    = (int2*)alloc((size_t)E * 8);
  bf16* t1g = aggC;                       // overlay: aggC dead after k_mf0
  bf16* t1r = t1g + (size_t)N * 128;

  (void)hipMemsetAsync(bcnt, 0, (size_t)2 * NBMAX * 4, stream);

  dim3 gc((E + PACHUNK - 1) / PACHUNK, 2);
  k_bhist<<<gc, 256, 0, stream>>>(ei_in, ei_ou, E, bcnt, NB);
  k_bscan<<<2, 64, 0, stream>>>(bcnt, BO, bcur, NB);
  k_partA<<<gc, 256, 0, stream>>>(ei_in, ew_in, ei_ou, ew_ou, E, bcur, sI, sO, NB);
  dim3 gb(NB, 2);
  k_partB<<<gb, 256, 0, stream>>>(BO, bcur, sI, sO, eI, eO, offsI, offsO, N);
  k_wprep<<<(128 * 192 + 255) / 256, 256, 0, stream>>>(Wmi0, Wmo0, Wsh0, Wmi1, Wmo1, Wsh1, resW,
                                                       bmi0, bsi0, bmo0, bso0, bmi1, bsi1, bmo1, bso1,
                                                       Wst0, Wcat1, bi0, bo0, bi1, bo1);
  k_packall<<<(8192 + 255) / 256, 256, 0, stream>>>(Wst0, Wcat1, Wd, Wp0, Wp1, Wpd);
  k_prep0<<<(N * 128 + 255) / 256, 256, 0, stream>>>(x, pe, h0bf, N * 128);

  int ab = (N + 3) / 4;
  int mb = (N + 63) / 64;
  k_agg0<<<ab, 256, 0, stream>>>(h0bf, offsI, eI, offsO, eO, cin0, cou0, aggC, N);
  k_mf0<<<mb, 256, 0, stream>>>(aggC, Wp0, bi0, bo0, cin0, cou0, h0bf, h1bf, N);
  k_mf1<<<mb, 256, 0, stream>>>(h1bf, Wp1, t1g, t1r, N);

  float* logp = (float*)d_out;
  float* emb  = logp + (size_t)N * 128;
  k_agg1<<<ab, 256, 0, stream>>>(t1g, t1r, offsI, eI, offsO, eO, bi1, bo1, resb, cin1, cou1,
                                 h2b, emb, N);
  k_mfd<<<mb, 256, 0, stream>>>(h2b, Wpd, bd, logp, N);
}